// Round 8
// baseline (507.467 us; speedup 1.0000x reference)
//
#include <hip/hip_runtime.h>

typedef unsigned short u16;
typedef __bf16 bf16x8 __attribute__((ext_vector_type(8)));
typedef short s16x8 __attribute__((ext_vector_type(8)));
typedef float f32x4 __attribute__((ext_vector_type(4)));

#define NB 2
#define SS 2048
#define DM 1024
#define NH 16
#define DH 64
#define DFF 4096

__device__ __forceinline__ u16 f2bf(float f) {
    unsigned u = __float_as_uint(f);
    u += 0x7fff + ((u >> 16) & 1);   // RNE
    return (u16)(u >> 16);
}
__device__ __forceinline__ float bf2f(u16 h) {
    return __uint_as_float(((unsigned)h) << 16);
}
// async global->LDS, 16B per lane. LDS dest must be wave-uniform base + lane*16.
__device__ __forceinline__ void gld_lds16(const void* g, void* l) {
    __builtin_amdgcn_global_load_lds(
        (const __attribute__((address_space(1))) unsigned int*)(size_t)g,
        (__attribute__((address_space(3))) unsigned int*)(unsigned)(size_t)l,
        16, 0, 0);
}
__device__ __forceinline__ float gelu_f(float x) {
    return 0.5f * x * (1.f + erff(x * 0.70710678118654752f));
}

// ---------------- weight convert + transpose: w[K][N] fp32 -> wt[N][K] bf16 ----
__global__ void wtrans_kernel(const float* __restrict__ w, u16* __restrict__ wt,
                              int K, int N) {
    __shared__ unsigned tl[64][65];
    int n0 = blockIdx.x * 64, k0 = blockIdx.y * 64, t = threadIdx.x;
    for (int it = 0; it < 16; ++it) {
        int e = it * 256 + t; int r = e >> 6, c = e & 63;       // r: k, c: n
        tl[r][c] = f2bf(w[(size_t)(k0 + r) * N + n0 + c]);
    }
    __syncthreads();
    for (int it = 0; it < 16; ++it) {
        int e = it * 256 + t; int r = e >> 6, c = e & 63;       // r: n, c: k
        wt[(size_t)(n0 + r) * K + k0 + c] = (u16)tl[c][r];
    }
}

// batched version for the four 1024x1024 projection weights
__global__ void wtrans4_kernel(const float* __restrict__ a, const float* __restrict__ b,
                               const float* __restrict__ c, const float* __restrict__ d,
                               u16* __restrict__ oa, u16* __restrict__ ob,
                               u16* __restrict__ oc, u16* __restrict__ od) {
    __shared__ unsigned tl[64][65];
    const float* w; u16* wt;
    switch (blockIdx.z) {
        case 0: w = a; wt = oa; break;
        case 1: w = b; wt = ob; break;
        case 2: w = c; wt = oc; break;
        default: w = d; wt = od; break;
    }
    int n0 = blockIdx.x * 64, k0 = blockIdx.y * 64, t = threadIdx.x;
    for (int it = 0; it < 16; ++it) {
        int e = it * 256 + t; int r = e >> 6, cc = e & 63;
        tl[r][cc] = f2bf(w[(size_t)(k0 + r) * DM + n0 + cc]);
    }
    __syncthreads();
    for (int it = 0; it < 16; ++it) {
        int e = it * 256 + t; int r = e >> 6, cc = e & 63;
        wt[(size_t)(n0 + r) * DM + k0 + cc] = (u16)tl[cc][r];
    }
}

// ---------------- aux: per-k-tile global bitmasks + concat QKV bias ----------
__global__ void build_aux(const int* __restrict__ gti, unsigned long long* __restrict__ kmask,
                          const float* __restrict__ bq, const float* __restrict__ bk,
                          const float* __restrict__ bv, float* __restrict__ bias3) {
    int t = threadIdx.x;
    if (t < 32) {
        unsigned long long m = 0ull;
        #pragma unroll
        for (int i = 0; i < 8; ++i) {
            int g = gti[i];
            if ((g >> 6) == t) m |= 1ull << (g & 63);
        }
        kmask[t] = m;
    }
    for (int i = t; i < 1024; i += 256) {
        bias3[i] = bq[i]; bias3[1024 + i] = bk[i]; bias3[2048 + i] = bv[i];
    }
}

// ---------------- LayerNorm: fp32 in -> bf16 out; INIT also writes iout=x+ib --
template <bool INIT>
__global__ __launch_bounds__(256) void ln_kernel(const float* __restrict__ x,
                                                 const float* __restrict__ g,
                                                 const float* __restrict__ b,
                                                 u16* __restrict__ out,
                                                 const float* __restrict__ ib,
                                                 float* __restrict__ iout) {
    int row = blockIdx.x, t = threadIdx.x;
    const float4 v = ((const float4*)(x + (size_t)row * DM))[t];
    float s  = v.x + v.y + v.z + v.w;
    float sq = v.x * v.x + v.y * v.y + v.z * v.z + v.w * v.w;
    #pragma unroll
    for (int m = 1; m < 64; m <<= 1) { s += __shfl_xor(s, m); sq += __shfl_xor(sq, m); }
    __shared__ float ss[4], ssq[4];
    int wv = t >> 6, lane = t & 63;
    if (lane == 0) { ss[wv] = s; ssq[wv] = sq; }
    __syncthreads();
    s  = ss[0] + ss[1] + ss[2] + ss[3];
    sq = ssq[0] + ssq[1] + ssq[2] + ssq[3];
    float mean = s * (1.f / DM);
    float var  = sq * (1.f / DM) - mean * mean;
    float rs   = rsqrtf(var + 1e-5f);
    float4 gg = ((const float4*)g)[t];
    float4 bb = ((const float4*)b)[t];
    ushort4 o;
    o.x = f2bf((v.x - mean) * rs * gg.x + bb.x);
    o.y = f2bf((v.y - mean) * rs * gg.y + bb.y);
    o.z = f2bf((v.z - mean) * rs * gg.z + bb.z);
    o.w = f2bf((v.w - mean) * rs * gg.w + bb.w);
    ((ushort4*)(out + (size_t)row * DM))[t] = o;
    if (INIT) {
        float4 b2 = ((const float4*)ib)[t];
        float4 iv; iv.x = v.x + b2.x; iv.y = v.y + b2.y; iv.z = v.z + b2.z; iv.w = v.w + b2.w;
        ((float4*)(iout + (size_t)row * DM))[t] = iv;
    }
}

// ---------------- RoPE: qkv bf16 [B,S,3072] -> head-major bf16 [B,H,S,Dh] ----
// Q is prescaled by 1/sqrt(Dh)=0.125 so attention needs no score scaling.
__global__ __launch_bounds__(256) void rope_kernel(const u16* __restrict__ qkv,
                                                   u16* __restrict__ qh,
                                                   u16* __restrict__ kh) {
    int idx = blockIdx.x * 256 + threadIdx.x;   // B*H*S*32 threads
    int d = idx & 31;
    int s = (idx >> 5) & (SS - 1);
    int h = (idx >> 16) & (NH - 1);
    int b = idx >> 20;
    size_t src = ((size_t)(b * SS + s)) * 3072 + h * DH + d;
    size_t dst = ((size_t)((b * NH + h) * SS + s)) * DH + d;
    float inv = powf(10000.f, -(float)d * (1.f / 32.f));
    float ang = (float)s * inv;
    float sn, cs;
    sincosf(ang, &sn, &cs);
    const float QSC = 0.125f;
    float x1 = bf2f(qkv[src]), x2 = bf2f(qkv[src + 32]);
    qh[dst]      = f2bf((x1 * cs - x2 * sn) * QSC);
    qh[dst + 32] = f2bf((x2 * cs + x1 * sn) * QSC);
    x1 = bf2f(qkv[src + 1024]); x2 = bf2f(qkv[src + 1024 + 32]);
    kh[dst]      = f2bf(x1 * cs - x2 * sn);
    kh[dst + 32] = f2bf(x2 * cs + x1 * sn);
}

// ---------------- V transpose: qkv [B,S,3072] (v at +2048) -> [B,H,Dh,S] -----
__global__ __launch_bounds__(256) void vtrans_kernel(const u16* __restrict__ qkv,
                                                     u16* __restrict__ vt) {
    __shared__ unsigned tile[64][65];
    int st = blockIdx.x, bh = blockIdx.y;
    int b = bh >> 4, h = bh & 15, t = threadIdx.x;
    const u16* src = qkv + ((size_t)b * SS + st * 64) * 3072 + 2048 + h * DH;
    for (int it = 0; it < 16; ++it) {
        int e = it * 256 + t; int r = e >> 6, c = e & 63;       // r: s, c: d
        tile[r][c] = src[(size_t)r * 3072 + c];
    }
    __syncthreads();
    u16* dst = vt + ((size_t)bh * DH) * SS + st * 64;
    for (int it = 0; it < 16; ++it) {
        int e = it * 256 + t; int d = e >> 6, s = e & 63;
        dst[(size_t)d * SS + s] = (u16)tile[s][d];
    }
}

// XCD-aware remap: dispatch slot s -> (bn, bm, bz) so that slots on the same
// XCD (s & 7 under round-robin) share A-row panels (same bm chunk).
// Requires gridDim.y % 8 == 0.
__device__ __forceinline__ void xcd_remap(int& bn, int& bm, int& bz) {
    int s = blockIdx.x + gridDim.x * (blockIdx.y + gridDim.y * blockIdx.z);
    int q = gridDim.y >> 3;                  // bm chunk per XCD
    int xcd = s & 7, lin = s >> 3;
    bm = xcd * q + (lin % q);
    int rest = lin / q;
    bn = rest % gridDim.x;
    bz = rest / gridDim.x;
}

// ---------------- GEMM (128x128, BK=32): C[M,N] = A[M,K](bf16) * Bt[N,K]^T ---
// MODE 0: +bias -> bf16 (QKV). MODE 1: +bias+res -> fp32 (Wo).
// MODE 3: split-K partial, atomicAdd fp32 (MLP2).
// BK=32 halves LDS to 32 KB -> 4-5 blocks/CU (was 2): barrier drains of one
// block overlap with compute of 3-4 others (m114 model). Swizzle re-derived
// for 64B rows: stage slot (c&3)^((r>>1)&3), read slot lq^((row>>1)&3);
// bank = 16(r&1)+4*slot -> 16 fragment rows cover 8 bank-groups 2x = free.
template <int MODE, int REMAP>
__global__ __launch_bounds__(256) void gemm_bt(const u16* __restrict__ A,
                                               const u16* __restrict__ Bt,
                                               const float* __restrict__ bias,
                                               const float* __restrict__ res,
                                               void* __restrict__ Cout,
                                               int M, int N, int K, int ldk) {
    int bnb = blockIdx.x, bmb = blockIdx.y, bzb = blockIdx.z;
    if (REMAP) xcd_remap(bnb, bmb, bzb);
    const int bm = bmb * 128, bn = bnb * 128;
    const int koff = bzb * K;
    const int t = threadIdx.x, wv = t >> 6, lane = t & 63;
    const int lr = lane & 15, lq = lane >> 4;
    const int wm = (wv >> 1) * 64, wn = (wv & 1) * 64;
    __shared__ __align__(16) u16 As[2][128 * 32];   // [m][k] swizzled, 8 KB each
    __shared__ __align__(16) u16 Bs[2][128 * 32];   // [n][k] swizzled
    f32x4 acc[4][4] = {};

    // stage one BK=32 tile (8 KB per matrix): 2 chunks/thread/matrix
    auto stage = [&](int kb, int buf) {
        #pragma unroll
        for (int p = 0; p < 2; ++p) {
            int c = p * 256 + t;                      // chunk id 0..511, 16B
            int r = c >> 2;                           // row 0..127
            int gc = ((c & 3) ^ ((r >> 1) & 3)) * 8;  // pre-swizzled source col
            gld_lds16(A + (size_t)(bm + r) * ldk + kb + gc,
                      As[buf] + (size_t)(p * 256 + wv * 64) * 8);
            gld_lds16(Bt + (size_t)(bn + r) * ldk + kb + gc,
                      Bs[buf] + (size_t)(p * 256 + wv * 64) * 8);
        }
    };

    stage(koff, 0);
    int pb = 0;
    for (int k0 = 0; k0 < K; k0 += 32) {
        __syncthreads();                       // buf pb complete for all waves
        if (k0 + 32 < K) stage(koff + k0 + 32, pb ^ 1);
        const u16* Ac = As[pb];
        const u16* Bc = Bs[pb];
        bf16x8 af[4], bfr[4];
        #pragma unroll
        for (int mi = 0; mi < 4; ++mi) {
            int row = wm + mi * 16 + lr;
            af[mi] = *(const bf16x8*)&Ac[row * 32 + ((lq ^ ((row >> 1) & 3)) * 8)];
        }
        #pragma unroll
        for (int ni = 0; ni < 4; ++ni) {
            int row = wn + ni * 16 + lr;
            bfr[ni] = *(const bf16x8*)&Bc[row * 32 + ((lq ^ ((row >> 1) & 3)) * 8)];
        }
        #pragma unroll
        for (int mi = 0; mi < 4; ++mi)
            #pragma unroll
            for (int ni = 0; ni < 4; ++ni)
                acc[mi][ni] = __builtin_amdgcn_mfma_f32_16x16x32_bf16(af[mi], bfr[ni], acc[mi][ni], 0, 0, 0);
        pb ^= 1;
    }
    #pragma unroll
    for (int mi = 0; mi < 4; ++mi) {
        int row0 = bm + wm + mi * 16 + lq * 4;
        #pragma unroll
        for (int ni = 0; ni < 4; ++ni) {
            int col = bn + wn + ni * 16 + lr;
            float bv = (MODE == 3) ? 0.f : bias[col];
            #pragma unroll
            for (int r = 0; r < 4; ++r) {
                float v = acc[mi][ni][r] + bv;
                size_t off = (size_t)(row0 + r) * N + col;
                if (MODE == 1) v += res[off];
                if (MODE == 2) v = gelu_f(v);
                if (MODE == 0 || MODE == 2) ((u16*)Cout)[off] = f2bf(v);
                else if (MODE == 1)         ((float*)Cout)[off] = v;
                else                        atomicAdd((float*)Cout + off, v);
            }
        }
    }
}

// ---------------- GEMM 256x256: 8-phase, deep counted-vmcnt, imm-offset LDS --
// (r5 structure, unchanged; used for MLP1 where the 16x16 grid = 1 block/CU.)
// MODE 2: gelu(+bias) -> bf16.  Requires NT even >= 4, gridDim.y % 8 == 0.
template <int MODE, int REMAP>
__global__ __launch_bounds__(512, 2) void gemm256(const u16* __restrict__ A,
                                                  const u16* __restrict__ Bt,
                                                  const float* __restrict__ bias,
                                                  void* __restrict__ Cout,
                                                  int M, int N, int K, int ldk) {
    int bnb = blockIdx.x, bmb = blockIdx.y, bzb = blockIdx.z;
    if (REMAP) xcd_remap(bnb, bmb, bzb);
    const int bm = bmb * 256, bn = bnb * 256;
    const int t = threadIdx.x, wv = t >> 6, lane = t & 63;
    const int lr = lane & 15, lq = lane >> 4;
    const int wm = (wv >> 2) * 128, wn = (wv & 3) * 64;
    const int awb = (wv >> 2) * 64;          // A group-local wave base
    const int bwb = (wv & 3) * 32;           // B group-local wave base
    __shared__ __align__(16) u16 As[2 * 2 * 128 * 64];   // [db][grp][128][64]
    __shared__ __align__(16) u16 Bs[2 * 2 * 128 * 64];
    f32x4 acc[8][4] = {};
    bf16x8 aA[4][2], bA[2][2], bB[2][2];

    const int aix0 = (awb + lr) * 64 + ((lq ^ (lr & 7)) * 8);
    const int aix1 = aix0 ^ 32;              // ks=1: slot^4 -> elem^32
    const int bix0 = (bwb + lr) * 64 + ((lq ^ (lr & 7)) * 8);
    const int bix1 = bix0 ^ 32;

    const u16 *pAsrc[2][2], *pBsrc[2][2];
    #pragma unroll
    for (int g = 0; g < 2; ++g)
        #pragma unroll
        for (int p = 0; p < 2; ++p) {
            int c = p * 512 + t;                         // chunk 0..1023
            int glr = c >> 3, sl = c & 7;                // group-local row, slot
            int sc = (sl ^ (glr & 7)) * 8;               // pre-swizzled col
            int grA = (glr & 63) + g * 64 + ((glr >> 6) << 7);
            int grB = (glr & 31) + g * 32 + ((glr >> 5) << 6);
            pAsrc[g][p] = A  + (size_t)(bm + grA) * ldk + sc;
            pBsrc[g][p] = Bt + (size_t)(bn + grB) * ldk + sc;
        }
    auto stA = [&](int g, int db, int ku) {
        #pragma unroll
        for (int p = 0; p < 2; ++p)
            gld_lds16(pAsrc[g][p] + ku, As + (size_t)(db * 2 + g) * 8192
                                           + (size_t)(p * 512 + wv * 64) * 8);
    };
    auto stB = [&](int g, int db, int ku) {
        #pragma unroll
        for (int p = 0; p < 2; ++p)
            gld_lds16(pBsrc[g][p] + ku, Bs + (size_t)(db * 2 + g) * 8192
                                           + (size_t)(p * 512 + wv * 64) * 8);
    };
    auto mmac = [&](int qm, int qn, bf16x8 (&bb)[2][2]) {      // 16 MFMA
        __builtin_amdgcn_s_setprio(1);
        #pragma unroll
        for (int mi2 = 0; mi2 < 4; ++mi2)
            #pragma unroll
            for (int ni2 = 0; ni2 < 2; ++ni2)
                #pragma unroll
                for (int ks = 0; ks < 2; ++ks)
                    acc[qm * 4 + mi2][qn * 2 + ni2] =
                        __builtin_amdgcn_mfma_f32_16x16x32_bf16(
                            aA[mi2][ks], bb[ni2][ks], acc[qm * 4 + mi2][qn * 2 + ni2], 0, 0, 0);
        __builtin_amdgcn_s_setprio(0);
    };
    #define BAR       __builtin_amdgcn_s_barrier()
    #define VMW(n)    asm volatile("s_waitcnt vmcnt(" #n ")" ::: "memory")
    #define LOADA(DB, G) do {                                                  \
        constexpr int O_ = ((DB) * 2 + (G)) * 8192;                            \
        aA[0][0] = *(const bf16x8*)&As[aix0 + O_];                             \
        aA[0][1] = *(const bf16x8*)&As[aix1 + O_];                             \
        aA[1][0] = *(const bf16x8*)&As[aix0 + O_ + 1024];                      \
        aA[1][1] = *(const bf16x8*)&As[aix1 + O_ + 1024];                      \
        aA[2][0] = *(const bf16x8*)&As[aix0 + O_ + 2048];                      \
        aA[2][1] = *(const bf16x8*)&As[aix1 + O_ + 2048];                      \
        aA[3][0] = *(const bf16x8*)&As[aix0 + O_ + 3072];                      \
        aA[3][1] = *(const bf16x8*)&As[aix1 + O_ + 3072];                      \
    } while (0)
    #define LOADB(DB, G, DST) do {                                             \
        constexpr int O_ = ((DB) * 2 + (G)) * 8192;                            \
        DST[0][0] = *(const bf16x8*)&Bs[bix0 + O_];                            \
        DST[0][1] = *(const bf16x8*)&Bs[bix1 + O_];                            \
        DST[1][0] = *(const bf16x8*)&Bs[bix0 + O_ + 1024];                     \
        DST[1][1] = *(const bf16x8*)&Bs[bix1 + O_ + 1024];                     \
    } while (0)
    #define G256_TILE(DB, KT) do {                                             \
        const int ku1 = ((KT) + 1) << 6, ku2 = ((KT) + 2) << 6;                \
        LOADA(DB, 0); LOADB(DB, 0, bA);          /* ph0: quadrant (0,0) */     \
        stA(1, (DB) ^ 1, ku1);                                                 \
        BAR;                                                                   \
        mmac(0, 0, bA);                                                        \
        VMW(6); BAR;                                                           \
        LOADB(DB, 1, bB);                        /* ph1: quadrant (0,1) */     \
        stB(1, (DB) ^ 1, ku1);                                                 \
        BAR;                                                                   \
        mmac(0, 1, bB);                                                        \
        BAR;                                                                   \
        LOADA(DB, 1);                            /* ph2: quadrant (1,1) */     \
        stA(0, DB, ku2);                                                       \
        BAR;                                                                   \
        mmac(1, 1, bB);                                                        \
        BAR;                                                                   \
        stB(0, DB, ku2);                         /* ph3: quadrant (1,0) */     \
        BAR;                                                                   \
        mmac(1, 0, bA);                                                        \
        VMW(8); BAR;                                                           \
    } while (0)

    const int NT = K >> 6;                 // K-tiles of 64; NT even, >= 4
    stA(0, 0, 0); stB(0, 0, 0); stA(1, 0, 0); stB(1, 0, 0);
    stA(0, 1, 64); stB(0, 1, 64);
    VMW(8);
    BAR;

    for (int kt = 0; kt + 4 <= NT; kt += 2) {
        G256_TILE(0, kt);
        G256_TILE(1, kt + 1);
    }
    {   // peeled tile NT-2 (db = 0 since NT even): only A1/B1(NT-1) to issue
        const int ku1 = (NT - 1) << 6;
        LOADA(0, 0); LOADB(0, 0, bA);
        stA(1, 1, ku1);
        BAR;
        mmac(0, 0, bA);
        VMW(6);
        BAR;
        LOADB(0, 1, bB);
        stB(1, 1, ku1);
        BAR;
        mmac(0, 1, bB);
        BAR;
        LOADA(0, 1);
        BAR;
        mmac(1, 1, bB);
        BAR;
        mmac(1, 0, bA);
        VMW(4);                           // retire A0(NT-1), B0(NT-1)
        BAR;
    }
    {   // peeled tile NT-1 (last, db = 1): no staging
        LOADA(1, 0); LOADB(1, 0, bA);
        BAR;
        mmac(0, 0, bA);
        VMW(0);                           // retire A1,B1(NT-1)
        BAR;
        LOADB(1, 1, bB);
        BAR;
        mmac(0, 1, bB);
        BAR;
        LOADA(1, 1);
        BAR;
        mmac(1, 1, bB);
        mmac(1, 0, bA);
    }
    #undef G256_TILE
    #undef LOADA
    #undef LOADB
    #undef BAR
    #undef VMW

    #pragma unroll
    for (int mi = 0; mi < 8; ++mi) {
        int row0 = bm + wm + mi * 16 + lq * 4;
        #pragma unroll
        for (int ni = 0; ni < 4; ++ni) {
            int col = bn + wn + ni * 16 + lr;
            float bv = bias[col];
            #pragma unroll
            for (int r = 0; r < 4; ++r) {
                float v = acc[mi][ni][r] + bv;
                size_t off = (size_t)(row0 + r) * N + col;
                if (MODE == 2) v = gelu_f(v);
                ((u16*)Cout)[off] = f2bf(v);
            }
        }
    }
}

// ---------------- Flash attention, band 512 + global-K tiles -----------------
__global__ __launch_bounds__(256) void attn_kernel(const u16* __restrict__ qh,
                                                   const u16* __restrict__ kh,
                                                   const u16* __restrict__ vt,
                                                   const unsigned long long* __restrict__ kmask,
                                                   u16* __restrict__ ctx) {
    const int qt = blockIdx.x, bh = blockIdx.y;
    const int b = bh >> 4, h = bh & 15;
    const int t = threadIdx.x, wv = t >> 6, lane = t & 63;
    const int lr = lane & 15, lq = lane >> 4;
    const int q0 = qt * 64;

    __shared__ __align__(16) u16 Qs[64 * 64];
    __shared__ __align__(16) u16 Ks[2][64 * 64];
    __shared__ __align__(16) u16 Vs[2][64 * 64];
    __shared__ __align__(16) u16 Ps[64 * 64];

    const u16* qbase = qh + ((size_t)bh * SS) * DH;
    const u16* kbase = kh + ((size_t)bh * SS) * DH;
    const u16* vbase = vt + ((size_t)bh * DH) * SS;

    #pragma unroll
    for (int p = 0; p < 2; ++p) {
        int c = p * 256 + t; int r = c >> 3, sl = c & 7;
        gld_lds16(qbase + (size_t)(q0 + r) * DH + ((sl ^ (r & 7)) * 8),
                  Qs + (size_t)(p * 256 + wv * 64) * 8);
    }

    float sum_part[4] = {0.f, 0.f, 0.f, 0.f};
    f32x4 acc_o[4] = {};

    const int lim = qt - 8;        // kt >= lim always included (band)
    int cur = 0;
    while (cur < lim && kmask[cur] == 0ull) ++cur;
    {
        int k0 = cur * 64;
        #pragma unroll
        for (int p = 0; p < 2; ++p) {
            int c = p * 256 + t; int r = c >> 3; int gc = ((c & 7) ^ (r & 7)) * 8;
            gld_lds16(kbase + (size_t)(k0 + r) * DH + gc, Ks[0] + (size_t)(p * 256 + wv * 64) * 8);
            gld_lds16(vbase + (size_t)r * SS + k0 + gc,  Vs[0] + (size_t)(p * 256 + wv * 64) * 8);
        }
    }
    int pb = 0;
    while (cur >= 0) {
        int nxt = cur + 1;
        while (nxt < lim && kmask[nxt] == 0ull) ++nxt;
        if (nxt > qt) nxt = -1;
        __syncthreads();                       // buf pb ready for all waves
        if (nxt >= 0) {
            int k0n = nxt * 64;
            #pragma unroll
            for (int p = 0; p < 2; ++p) {
                int c = p * 256 + t; int r = c >> 3; int gc = ((c & 7) ^ (r & 7)) * 8;
                gld_lds16(kbase + (size_t)(k0n + r) * DH + gc, Ks[pb ^ 1] + (size_t)(p * 256 + wv * 64) * 8);
                gld_lds16(vbase + (size_t)r * SS + k0n + gc,  Vs[pb ^ 1] + (size_t)(p * 256 + wv * 64) * 8);
            }
        }
        const u16* Kt = Ks[pb];
        const u16* Vt = Vs[pb];
        const int k0 = cur * 64;

        f32x4 s_acc[4] = {};
        #pragma unroll
        for (int ks = 0; ks < 2; ++ks) {
            const int arow = wv * 16 + lr;
            bf16x8 af = *(const bf16x8*)&Qs[arow * 64 + (((ks * 4 + lq) ^ (arow & 7)) * 8)];
            #pragma unroll
            for (int ni = 0; ni < 4; ++ni) {
                const int brow = ni * 16 + lr;
                bf16x8 bfr = *(const bf16x8*)&Kt[brow * 64 + (((ks * 4 + lq) ^ (brow & 7)) * 8)];
                s_acc[ni] = __builtin_amdgcn_mfma_f32_16x16x32_bf16(af, bfr, s_acc[ni], 0, 0, 0);
            }
        }
        float sv[4][4];
        if (cur >= qt - 7 && cur != qt) {                    // FULL
            #pragma unroll
            for (int ni = 0; ni < 4; ++ni)
                #pragma unroll
                for (int r = 0; r < 4; ++r) sv[ni][r] = __expf(s_acc[ni][r]);
        } else if (cur == qt) {                              // DIAG
            #pragma unroll
            for (int ni = 0; ni < 4; ++ni) {
                int j = ni * 16 + lr;
                #pragma unroll
                for (int r = 0; r < 4; ++r) {
                    int i = wv * 16 + lq * 4 + r;
                    float p = __expf(s_acc[ni][r]);
                    sv[ni][r] = (j <= i) ? p : 0.f;
                }
            }
        } else {                                             // MASKED
            unsigned long long cm = kmask[cur];
            #pragma unroll
            for (int ni = 0; ni < 4; ++ni) {
                int j = k0 + ni * 16 + lr;
                bool gj = (cm >> (ni * 16 + lr)) & 1ull;
                #pragma unroll
                for (int r = 0; r < 4; ++r) {
                    int i = q0 + wv * 16 + lq * 4 + r;
                    bool ok = ((i - j) < 512) | gj;
                    float p = __expf(s_acc[ni][r]);
                    sv[ni][r] = ok ? p : 0.f;
                }
            }
        }
        #pragma unroll
        for (int ni = 0; ni < 4; ++ni) {
            int col = ni * 16 + lr;
            #pragma unroll
            for (int r = 0; r < 4; ++r) {
                int row = wv * 16 + lq * 4 + r;
                sum_part[r] += sv[ni][r];
                Ps[row * 64 + (((col >> 3) ^ (row & 7)) * 8) + (col & 7)] = f2bf(sv[ni][r]);
            }
        }
        #pragma unroll
        for (int ks = 0; ks < 2; ++ks) {
            const int arow = wv * 16 + lr;
            bf16x8 af = *(const bf16x8*)&Ps[arow * 64 + (((ks * 4 + lq) ^ (arow & 7)) * 8)];
            #pragma unroll
            for (int ni = 0; ni < 4; ++ni) {
                const int brow = ni * 16 + lr;
                bf16x8 bfr = *(const bf16x8*)&Vt[brow * 64 + (((ks * 4 + lq) ^ (brow & 7)) * 8)];
                acc_o[ni] = __builtin_amdgcn_mfma_f32_16x16x32_bf16(af, bfr, acc_o[ni], 0, 0, 0);
            }
        }
        cur = nxt; pb ^= 1;
    }
    float inv_l[4];
    #pragma unroll
    for (int r = 0; r < 4; ++r) {
        float ls = sum_part[r];
        #pragma unroll
        for (int m = 1; m < 16; m <<= 1) ls += __shfl_xor(ls, m, 16);
        inv_l[r] = 1.f / ls;
    }
    u16* obase = ctx + ((size_t)b * SS) * DM + h * DH;
    #pragma unroll
    for (int ni = 0; ni < 4; ++ni)
        #pragma unroll
        for (int r = 0; r < 4; ++r) {
            int i = q0 + wv * 16 + lq * 4 + r;
            obase[(size_t)i * DM + ni * 16 + lr] = f2bf(acc_o[ni][r] * inv_l[r]);
        }
}

// ---------------- Global-row fixup: lane = key, zero in-loop cross-lane ops --
__global__ __launch_bounds__(256) void attn_fix_kernel(const u16* __restrict__ qh,
                                                       const u16* __restrict__ kh,
                                                       const u16* __restrict__ qkv,
                                                       const int* __restrict__ gti,
                                                       u16* __restrict__ ctx) {
    const int gidx = blockIdx.x, bh = blockIdx.y;
    const int b = bh >> 4, h = bh & 15;
    const int t = threadIdx.x, wv = t >> 6, lane = t & 63;
    const int i = gti[gidx];

    __shared__ float qsh[64];
    if (t < 64) qsh[t] = bf2f(qh[((size_t)bh * SS + i) * DH + t]);   // RoPE'd, prescaled
    __syncthreads();
    float qreg[64];
    #pragma unroll
    for (int c = 0; c < 16; ++c) {
        float4 qv = ((const float4*)qsh)[c];   // broadcast
        qreg[c * 4 + 0] = qv.x; qreg[c * 4 + 1] = qv.y;
        qreg[c * 4 + 2] = qv.z; qreg[c * 4 + 3] = qv.w;
    }

    const u16* kb = kh + (size_t)bh * SS * DH;
    const u16* vb = qkv + (size_t)b * SS * 3072 + 2048 + h * DH;

    float Oacc[64];
    #pragma unroll
    for (int d = 0; d < 64; ++d) Oacc[d] = 0.f;
    float lacc = 0.f;

    for (int j0 = wv * 64; j0 <= i; j0 += 256) {
        const int j = j0 + lane;
        const bool valid = (j <= i);
        const int jc = valid ? j : i;
        const s16x8* krow = (const s16x8*)(kb + (size_t)jc * DH);
        float part[8];
        #pragma unroll
        for (int c = 0; c < 8; ++c) {
            s16x8 kv = krow[c];
            float p0 = 0.f;
            #pragma unroll
            for (int e = 0; e < 8; ++e) p0 += qreg[c * 8 + e] * bf2f((u16)kv[e]);
            part[c] = p0;
        }
        float s = ((part[0] + part[1]) + (part[2] + part[3])) +
                  ((part[4] + part[5]) + (part[6] + part[7]));
        const float p = valid ? __expf(s) : 0.f;
        lacc += p;
        const s16x8* vrow = (const s16x8*)(vb + (size_t)jc * 3072);
        #pragma unroll
        for (int c = 0; c < 8; ++c) {
            s16x8 vv = vrow[c];
            #pragma unroll
            for (int e = 0; e < 8; ++e) Oacc[c * 8 + e] += p * bf2f((u16)vv[e]);
        }
    }
    #pragma unroll
    for (int m = 1; m < 64; m <<= 1) {
        lacc += __shfl_xor(lacc, m);
        #pragma unroll
        for (int d = 0; d < 64; ++d) Oacc[d] += __shfl_xor(Oacc[d], m);
    }
    float out = 0.f;
    #pragma unroll
    for (int d = 0; d < 64; ++d) out = (lane == d) ? Oacc[d] : out;
    __shared__ float osum[4][64];
    __shared__ float lsum[4];
    osum[wv][lane] = out;
    if (lane == 0) lsum[wv] = lacc;
    __syncthreads();
    if (wv == 0) {
        float ot = osum[0][lane] + osum[1][lane] + osum[2][lane] + osum[3][lane];
        float lt = lsum[0] + lsum[1] + lsum[2] + lsum[3];
        ctx[((size_t)b * SS + i) * DM + h * DH + lane] = f2bf(ot / lt);
    }
}

extern "C" void kernel_launch(void* const* d_in, const int* in_sizes, int n_in,
                              void* d_out, int out_size, void* d_ws, size_t ws_size,
                              hipStream_t stream) {
    (void)in_sizes; (void)n_in; (void)out_size; (void)ws_size;
    const float* hidden = (const float*)d_in[0];
    const float* ln1_g  = (const float*)d_in[1];
    const float* ln1_b  = (const float*)d_in[2];
    const float* wq = (const float*)d_in[3];  const float* bq = (const float*)d_in[4];
    const float* wk = (const float*)d_in[5];  const float* bk = (const float*)d_in[6];
    const float* wv = (const float*)d_in[7];  const float* bv = (const float*)d_in[8];
    const float* wo = (const float*)d_in[9];  const float* bo = (const float*)d_in[10];
    const float* ln2_g = (const float*)d_in[11];
    const float* ln2_b = (const float*)d_in[12];
    const float* w1 = (const float*)d_in[13]; const float* b1 = (const float*)d_in[14];
    const float* w2 = (const float*)d_in[15]; const float* b2 = (const float*)d_in[16];
    const int*  gti = (const int*)d_in[17];

    char* ws = (char*)d_ws;
    const size_t MB = 1u << 20;
    u16* wqt  = (u16*)(ws + 0 * MB);    // [3072][1024] contiguous (wq|wk|wv transposed)
    u16* wkt  = (u16*)(ws + 2 * MB);
    u16* wvt  = (u16*)(ws + 4 * MB);
    u16* wot  = (u16*)(ws + 6 * MB);
    u16* w1t  = (u16*)(ws + 8 * MB);    // [4096][1024]
    u16* w2t  = (u16*)(ws + 16 * MB);   // [1024][4096]
    u16* xb   = (u16*)(ws + 24 * MB);   // ln1 out; reused as ctx after QKV
    u16* ctx  = xb;
    u16* qkv  = (u16*)(ws + 32 * MB);   // [4096][3072] bf16, 24MB (32..56)
    u16* qhb  = (u16*)(ws + 56 * MB);
    u16* khb  = (u16*)(ws + 64 * MB);
    u16* vtb  = (u16*)(ws + 72 * MB);
    float* hb = (float*)(ws + 80 * MB); // fp32 residual h, 16MB
    u16* act  = (u16*)(ws + 32 * MB);   // 32MB (32..64): qkv+qhb dead after fixup
    u16* yb   = (u16*)(ws + 64 * MB);   // reuses khb (dead after fixup)
    unsigned long long* kmask = (unsigned long long*)(ws + 96 * MB);
    float* bias3 = (float*)(ws + 96 * MB + 8192);

    wtrans4_kernel<<<dim3(16, 16, 4), 256, 0, stream>>>(wq, wk, wv, wo, wqt, wkt, wvt, wot);
    wtrans_kernel<<<dim3(64, 16), 256, 0, stream>>>(w1, w1t, DM, DFF);
    wtrans_kernel<<<dim3(16, 64), 256, 0, stream>>>(w2, w2t, DFF, DM);
    build_aux<<<1, 256, 0, stream>>>(gti, kmask, bq, bk, bv, bias3);

    ln_kernel<false><<<NB * SS, 256, 0, stream>>>(hidden, ln1_g, ln1_b, xb, nullptr, nullptr);

    // fused QKV: 128^2 BK=32 gemm_bt, 768 blocks @ 3/CU+, all CUs busy
    gemm_bt<0, 1><<<dim3(24, 32), 256, 0, stream>>>(
        xb, wqt, bias3, nullptr, qkv, NB * SS, 3072, DM, DM);

    rope_kernel<<<(NB * NH * SS * 32) / 256, 256, 0, stream>>>(qkv, qhb, khb);
    vtrans_kernel<<<dim3(SS / 64, NB * NH), 256, 0, stream>>>(qkv, vtb);

    attn_kernel<<<dim3(SS / 64, NB * NH), 256, 0, stream>>>(qhb, khb, vtb, kmask, ctx);
    attn_fix_kernel<<<dim3(8, NB * NH), 256, 0, stream>>>(qhb, khb, qkv, gti, ctx);

    gemm_bt<1, 1><<<dim3(8, 32), 256, 0, stream>>>(ctx, wot, bo, hidden, hb, NB * SS, DM, DM, DM);
    // ln2 + init d_out = h + b2 (accumulation target for split-K w2)
    ln_kernel<true><<<NB * SS, 256, 0, stream>>>(hb, ln2_g, ln2_b, yb, b2, (float*)d_out);
    // MLP GEMM1: gelu(y @ w1 + b1) -> act  (256^2 8-phase, 256 blocks = 1/CU)
    gemm256<2, 1><<<dim3(DFF / 256, (NB * SS) / 256), 512, 0, stream>>>(
        yb, w1t, b1, act, NB * SS, DFF, DM, DM);
    // MLP GEMM2: split-K=2 (512 blocks): d_out += act * w2t^T  (XCD-remapped)
    gemm_bt<3, 1><<<dim3(8, 32, 2), 256, 0, stream>>>(act, w2t, nullptr, nullptr, d_out, NB * SS, DM, DFF / 2, DFF);
}

// Round 9
// 386.234 us; speedup vs baseline: 1.3139x; 1.3139x over previous
//
#include <hip/hip_runtime.h>

typedef unsigned short u16;
typedef __bf16 bf16x8 __attribute__((ext_vector_type(8)));
typedef short s16x8 __attribute__((ext_vector_type(8)));
typedef float f32x4 __attribute__((ext_vector_type(4)));

#define NB 2
#define SS 2048
#define DM 1024
#define NH 16
#define DH 64
#define DFF 4096

__device__ __forceinline__ u16 f2bf(float f) {
    unsigned u = __float_as_uint(f);
    u += 0x7fff + ((u >> 16) & 1);   // RNE
    return (u16)(u >> 16);
}
__device__ __forceinline__ float bf2f(u16 h) {
    return __uint_as_float(((unsigned)h) << 16);
}
// async global->LDS, 16B per lane. LDS dest must be wave-uniform base + lane*16.
__device__ __forceinline__ void gld_lds16(const void* g, void* l) {
    __builtin_amdgcn_global_load_lds(
        (const __attribute__((address_space(1))) unsigned int*)(size_t)g,
        (__attribute__((address_space(3))) unsigned int*)(unsigned)(size_t)l,
        16, 0, 0);
}
__device__ __forceinline__ float gelu_f(float x) {
    return 0.5f * x * (1.f + erff(x * 0.70710678118654752f));
}

// ---------------- weight convert + transpose: w[K][N] fp32 -> wt[N][K] bf16 ----
__global__ void wtrans_kernel(const float* __restrict__ w, u16* __restrict__ wt,
                              int K, int N) {
    __shared__ unsigned tl[64][65];
    int n0 = blockIdx.x * 64, k0 = blockIdx.y * 64, t = threadIdx.x;
    for (int it = 0; it < 16; ++it) {
        int e = it * 256 + t; int r = e >> 6, c = e & 63;       // r: k, c: n
        tl[r][c] = f2bf(w[(size_t)(k0 + r) * N + n0 + c]);
    }
    __syncthreads();
    for (int it = 0; it < 16; ++it) {
        int e = it * 256 + t; int r = e >> 6, c = e & 63;       // r: n, c: k
        wt[(size_t)(n0 + r) * K + k0 + c] = (u16)tl[c][r];
    }
}

// batched version for the four 1024x1024 projection weights
__global__ void wtrans4_kernel(const float* __restrict__ a, const float* __restrict__ b,
                               const float* __restrict__ c, const float* __restrict__ d,
                               u16* __restrict__ oa, u16* __restrict__ ob,
                               u16* __restrict__ oc, u16* __restrict__ od) {
    __shared__ unsigned tl[64][65];
    const float* w; u16* wt;
    switch (blockIdx.z) {
        case 0: w = a; wt = oa; break;
        case 1: w = b; wt = ob; break;
        case 2: w = c; wt = oc; break;
        default: w = d; wt = od; break;
    }
    int n0 = blockIdx.x * 64, k0 = blockIdx.y * 64, t = threadIdx.x;
    for (int it = 0; it < 16; ++it) {
        int e = it * 256 + t; int r = e >> 6, cc = e & 63;
        tl[r][cc] = f2bf(w[(size_t)(k0 + r) * DM + n0 + cc]);
    }
    __syncthreads();
    for (int it = 0; it < 16; ++it) {
        int e = it * 256 + t; int r = e >> 6, cc = e & 63;
        wt[(size_t)(n0 + r) * DM + k0 + cc] = (u16)tl[cc][r];
    }
}

// ---------------- aux: per-k-tile global bitmasks + concat QKV bias ----------
__global__ void build_aux(const int* __restrict__ gti, unsigned long long* __restrict__ kmask,
                          const float* __restrict__ bq, const float* __restrict__ bk,
                          const float* __restrict__ bv, float* __restrict__ bias3) {
    int t = threadIdx.x;
    if (t < 32) {
        unsigned long long m = 0ull;
        #pragma unroll
        for (int i = 0; i < 8; ++i) {
            int g = gti[i];
            if ((g >> 6) == t) m |= 1ull << (g & 63);
        }
        kmask[t] = m;
    }
    for (int i = t; i < 1024; i += 256) {
        bias3[i] = bq[i]; bias3[1024 + i] = bk[i]; bias3[2048 + i] = bv[i];
    }
}

// ---------------- LayerNorm: fp32 in -> bf16 out; INIT also writes iout=x+ib --
template <bool INIT>
__global__ __launch_bounds__(256) void ln_kernel(const float* __restrict__ x,
                                                 const float* __restrict__ g,
                                                 const float* __restrict__ b,
                                                 u16* __restrict__ out,
                                                 const float* __restrict__ ib,
                                                 float* __restrict__ iout) {
    int row = blockIdx.x, t = threadIdx.x;
    const float4 v = ((const float4*)(x + (size_t)row * DM))[t];
    float s  = v.x + v.y + v.z + v.w;
    float sq = v.x * v.x + v.y * v.y + v.z * v.z + v.w * v.w;
    #pragma unroll
    for (int m = 1; m < 64; m <<= 1) { s += __shfl_xor(s, m); sq += __shfl_xor(sq, m); }
    __shared__ float ss[4], ssq[4];
    int wv = t >> 6, lane = t & 63;
    if (lane == 0) { ss[wv] = s; ssq[wv] = sq; }
    __syncthreads();
    s  = ss[0] + ss[1] + ss[2] + ss[3];
    sq = ssq[0] + ssq[1] + ssq[2] + ssq[3];
    float mean = s * (1.f / DM);
    float var  = sq * (1.f / DM) - mean * mean;
    float rs   = rsqrtf(var + 1e-5f);
    float4 gg = ((const float4*)g)[t];
    float4 bb = ((const float4*)b)[t];
    ushort4 o;
    o.x = f2bf((v.x - mean) * rs * gg.x + bb.x);
    o.y = f2bf((v.y - mean) * rs * gg.y + bb.y);
    o.z = f2bf((v.z - mean) * rs * gg.z + bb.z);
    o.w = f2bf((v.w - mean) * rs * gg.w + bb.w);
    ((ushort4*)(out + (size_t)row * DM))[t] = o;
    if (INIT) {
        float4 b2 = ((const float4*)ib)[t];
        float4 iv; iv.x = v.x + b2.x; iv.y = v.y + b2.y; iv.z = v.z + b2.z; iv.w = v.w + b2.w;
        ((float4*)(iout + (size_t)row * DM))[t] = iv;
    }
}

// ---------------- RoPE: qkv bf16 [B,S,3072] -> head-major bf16 [B,H,S,Dh] ----
// Q is prescaled by 1/sqrt(Dh)=0.125 so attention needs no score scaling.
__global__ __launch_bounds__(256) void rope_kernel(const u16* __restrict__ qkv,
                                                   u16* __restrict__ qh,
                                                   u16* __restrict__ kh) {
    int idx = blockIdx.x * 256 + threadIdx.x;   // B*H*S*32 threads
    int d = idx & 31;
    int s = (idx >> 5) & (SS - 1);
    int h = (idx >> 16) & (NH - 1);
    int b = idx >> 20;
    size_t src = ((size_t)(b * SS + s)) * 3072 + h * DH + d;
    size_t dst = ((size_t)((b * NH + h) * SS + s)) * DH + d;
    float inv = powf(10000.f, -(float)d * (1.f / 32.f));
    float ang = (float)s * inv;
    float sn, cs;
    sincosf(ang, &sn, &cs);
    const float QSC = 0.125f;
    float x1 = bf2f(qkv[src]), x2 = bf2f(qkv[src + 32]);
    qh[dst]      = f2bf((x1 * cs - x2 * sn) * QSC);
    qh[dst + 32] = f2bf((x2 * cs + x1 * sn) * QSC);
    x1 = bf2f(qkv[src + 1024]); x2 = bf2f(qkv[src + 1024 + 32]);
    kh[dst]      = f2bf(x1 * cs - x2 * sn);
    kh[dst + 32] = f2bf(x2 * cs + x1 * sn);
}

// ---------------- V transpose: qkv [B,S,3072] (v at +2048) -> [B,H,Dh,S] -----
__global__ __launch_bounds__(256) void vtrans_kernel(const u16* __restrict__ qkv,
                                                     u16* __restrict__ vt) {
    __shared__ unsigned tile[64][65];
    int st = blockIdx.x, bh = blockIdx.y;
    int b = bh >> 4, h = bh & 15, t = threadIdx.x;
    const u16* src = qkv + ((size_t)b * SS + st * 64) * 3072 + 2048 + h * DH;
    for (int it = 0; it < 16; ++it) {
        int e = it * 256 + t; int r = e >> 6, c = e & 63;       // r: s, c: d
        tile[r][c] = src[(size_t)r * 3072 + c];
    }
    __syncthreads();
    u16* dst = vt + ((size_t)bh * DH) * SS + st * 64;
    for (int it = 0; it < 16; ++it) {
        int e = it * 256 + t; int d = e >> 6, s = e & 63;
        dst[(size_t)d * SS + s] = (u16)tile[s][d];
    }
}

// XCD-aware remap: dispatch slot s -> (bn, bm, bz) so that slots on the same
// XCD (s & 7 under round-robin) share A-row panels (same bm chunk).
// Requires gridDim.y % 8 == 0.
__device__ __forceinline__ void xcd_remap(int& bn, int& bm, int& bz) {
    int s = blockIdx.x + gridDim.x * (blockIdx.y + gridDim.y * blockIdx.z);
    int q = gridDim.y >> 3;                  // bm chunk per XCD
    int xcd = s & 7, lin = s >> 3;
    bm = xcd * q + (lin % q);
    int rest = lin / q;
    bn = rest % gridDim.x;
    bz = rest / gridDim.x;
}

// ---------------- GEMM (legacy 128x128): C[M,N] = A[M,K](bf16) * Bt[N,K]^T ---
// MODE 1: +bias+res -> fp32 (Wo). MODE 3: split-K partial, atomicAdd fp32.
template <int MODE, int REMAP>
__global__ __launch_bounds__(256) void gemm_bt(const u16* __restrict__ A,
                                               const u16* __restrict__ Bt,
                                               const float* __restrict__ bias,
                                               const float* __restrict__ res,
                                               void* __restrict__ Cout,
                                               int M, int N, int K, int ldk) {
    int bnb = blockIdx.x, bmb = blockIdx.y, bzb = blockIdx.z;
    if (REMAP) xcd_remap(bnb, bmb, bzb);
    const int bm = bmb * 128, bn = bnb * 128;
    const int koff = bzb * K;
    const int t = threadIdx.x, wv = t >> 6, lane = t & 63;
    const int lr = lane & 15, lq = lane >> 4;
    const int wm = (wv >> 1) * 64, wn = (wv & 1) * 64;
    __shared__ __align__(16) u16 As[2][128 * 64];   // [m][k] swizzled, 16 KB each
    __shared__ __align__(16) u16 Bs[2][128 * 64];   // [n][k] swizzled
    f32x4 acc[4][4] = {};

    auto stage = [&](int kb, int buf) {
        #pragma unroll
        for (int p = 0; p < 4; ++p) {
            int c = p * 256 + t;                 // chunk id 0..1023, 16B each
            int r = c >> 3;                      // row 0..127
            int gc = ((c & 7) ^ (r & 7)) * 8;    // swizzled source column
            gld_lds16(A + (size_t)(bm + r) * ldk + kb + gc,
                      As[buf] + (size_t)(p * 256 + wv * 64) * 8);
            gld_lds16(Bt + (size_t)(bn + r) * ldk + kb + gc,
                      Bs[buf] + (size_t)(p * 256 + wv * 64) * 8);
        }
    };

    stage(koff, 0);
    int pb = 0;
    for (int k0 = 0; k0 < K; k0 += 64) {
        __syncthreads();                       // buf pb complete for all waves
        if (k0 + 64 < K) stage(koff + k0 + 64, pb ^ 1);
        const u16* Ac = As[pb];
        const u16* Bc = Bs[pb];
        #pragma unroll
        for (int ks = 0; ks < 2; ++ks) {
            bf16x8 af[4], bfr[4];
            #pragma unroll
            for (int mi = 0; mi < 4; ++mi) {
                int row = wm + mi * 16 + lr;
                af[mi] = *(const bf16x8*)&Ac[row * 64 + (((ks * 4 + lq) ^ (row & 7)) * 8)];
            }
            #pragma unroll
            for (int ni = 0; ni < 4; ++ni) {
                int row = wn + ni * 16 + lr;
                bfr[ni] = *(const bf16x8*)&Bc[row * 64 + (((ks * 4 + lq) ^ (row & 7)) * 8)];
            }
            #pragma unroll
            for (int mi = 0; mi < 4; ++mi)
                #pragma unroll
                for (int ni = 0; ni < 4; ++ni)
                    acc[mi][ni] = __builtin_amdgcn_mfma_f32_16x16x32_bf16(af[mi], bfr[ni], acc[mi][ni], 0, 0, 0);
        }
        pb ^= 1;
    }
    #pragma unroll
    for (int mi = 0; mi < 4; ++mi) {
        int row0 = bm + wm + mi * 16 + lq * 4;
        #pragma unroll
        for (int ni = 0; ni < 4; ++ni) {
            int col = bn + wn + ni * 16 + lr;
            float bv = (MODE == 3) ? 0.f : bias[col];
            #pragma unroll
            for (int r = 0; r < 4; ++r) {
                float v = acc[mi][ni][r] + bv;
                size_t off = (size_t)(row0 + r) * N + col;
                if (MODE == 1) v += res[off];
                if (MODE == 2) v = gelu_f(v);
                if (MODE == 0 || MODE == 2) ((u16*)Cout)[off] = f2bf(v);
                else if (MODE == 1)         ((float*)Cout)[off] = v;
                else                        atomicAdd((float*)Cout + off, v);
            }
        }
    }
}

// ---------------- GEMM 256x256: 8-phase, deep counted-vmcnt, imm-offset LDS --
// Schedule as round-3/4 EXCEPT: no lgkmcnt(0) drain and no sched_barrier(0)
// per phase. All LDS reads are compiler-visible C++ loads, so the compiler
// emits fine-grained counted lgkmcnt waits before each dependent MFMA and is
// free to overlap LDS-return latency with MFMA issue (m141 lesson: pinning
// the order defeats the scheduler). Correctness: each phase's ds_reads are
// consumed by that phase's MFMAs (so they complete before the end-of-phase
// barrier), and cross-wave staging WAR/RAW is ordered by the barriers + the
// unchanged counted-vmcnt ledger:
//   ph0 stages A1(kt+1); ph1: B1(kt+1); ph2: A0(kt+2); ph3: B0(kt+2);
//   end-ph0: vmcnt(6) retires through B1(kt); end-ph3: vmcnt(8) retires
//   A0(kt+1), B0(kt+1). Never drained to 0 in the main loop.
// MODE 0: +bias -> bf16 ; MODE 2: gelu(+bias) -> bf16.  Requires NT even >= 4.
template <int MODE, int REMAP>
__global__ __launch_bounds__(512, 2) void gemm256(const u16* __restrict__ A,
                                                  const u16* __restrict__ Bt,
                                                  const float* __restrict__ bias,
                                                  void* __restrict__ Cout,
                                                  int M, int N, int K, int ldk) {
    int bnb = blockIdx.x, bmb = blockIdx.y, bzb = blockIdx.z;
    if (REMAP) xcd_remap(bnb, bmb, bzb);
    const int bm = bmb * 256, bn = bnb * 256;
    const int t = threadIdx.x, wv = t >> 6, lane = t & 63;
    const int lr = lane & 15, lq = lane >> 4;
    const int wm = (wv >> 2) * 128, wn = (wv & 3) * 64;
    const int awb = (wv >> 2) * 64;          // A group-local wave base
    const int bwb = (wv & 3) * 32;           // B group-local wave base
    __shared__ __align__(16) u16 As[2 * 2 * 128 * 64];   // [db][grp][128][64]
    __shared__ __align__(16) u16 Bs[2 * 2 * 128 * 64];
    f32x4 acc[8][4] = {};
    bf16x8 aA[4][2], bA[2][2], bB[2][2];

    // 4 per-lane LDS base indices (u16 units); everything else is an immediate.
    const int aix0 = (awb + lr) * 64 + ((lq ^ (lr & 7)) * 8);
    const int aix1 = aix0 ^ 32;              // ks=1: slot^4 -> elem^32
    const int bix0 = (bwb + lr) * 64 + ((lq ^ (lr & 7)) * 8);
    const int bix1 = bix0 ^ 32;

    // per-thread pre-swizzled staging source pointers (2 loads per half-tile)
    const u16 *pAsrc[2][2], *pBsrc[2][2];
    #pragma unroll
    for (int g = 0; g < 2; ++g)
        #pragma unroll
        for (int p = 0; p < 2; ++p) {
            int c = p * 512 + t;                         // chunk 0..1023
            int glr = c >> 3, sl = c & 7;                // group-local row, slot
            int sc = (sl ^ (glr & 7)) * 8;               // pre-swizzled col
            int grA = (glr & 63) + g * 64 + ((glr >> 6) << 7);
            int grB = (glr & 31) + g * 32 + ((glr >> 5) << 6);
            pAsrc[g][p] = A  + (size_t)(bm + grA) * ldk + sc;
            pBsrc[g][p] = Bt + (size_t)(bn + grB) * ldk + sc;
        }
    auto stA = [&](int g, int db, int ku) {
        #pragma unroll
        for (int p = 0; p < 2; ++p)
            gld_lds16(pAsrc[g][p] + ku, As + (size_t)(db * 2 + g) * 8192
                                           + (size_t)(p * 512 + wv * 64) * 8);
    };
    auto stB = [&](int g, int db, int ku) {
        #pragma unroll
        for (int p = 0; p < 2; ++p)
            gld_lds16(pBsrc[g][p] + ku, Bs + (size_t)(db * 2 + g) * 8192
                                           + (size_t)(p * 512 + wv * 64) * 8);
    };
    auto mmac = [&](int qm, int qn, bf16x8 (&bb)[2][2]) {      // 16 MFMA
        __builtin_amdgcn_s_setprio(1);
        #pragma unroll
        for (int mi2 = 0; mi2 < 4; ++mi2)
            #pragma unroll
            for (int ni2 = 0; ni2 < 2; ++ni2)
                #pragma unroll
                for (int ks = 0; ks < 2; ++ks)
                    acc[qm * 4 + mi2][qn * 2 + ni2] =
                        __builtin_amdgcn_mfma_f32_16x16x32_bf16(
                            aA[mi2][ks], bb[ni2][ks], acc[qm * 4 + mi2][qn * 2 + ni2], 0, 0, 0);
        __builtin_amdgcn_s_setprio(0);
    };
    #define BAR       __builtin_amdgcn_s_barrier()
    #define VMW(n)    asm volatile("s_waitcnt vmcnt(" #n ")" ::: "memory")
    // all-immediate LDS fragment loads (DB, G literals at every call site)
    #define LOADA(DB, G) do {                                                  \
        constexpr int O_ = ((DB) * 2 + (G)) * 8192;                            \
        aA[0][0] = *(const bf16x8*)&As[aix0 + O_];                             \
        aA[0][1] = *(const bf16x8*)&As[aix1 + O_];                             \
        aA[1][0] = *(const bf16x8*)&As[aix0 + O_ + 1024];                      \
        aA[1][1] = *(const bf16x8*)&As[aix1 + O_ + 1024];                      \
        aA[2][0] = *(const bf16x8*)&As[aix0 + O_ + 2048];                      \
        aA[2][1] = *(const bf16x8*)&As[aix1 + O_ + 2048];                      \
        aA[3][0] = *(const bf16x8*)&As[aix0 + O_ + 3072];                      \
        aA[3][1] = *(const bf16x8*)&As[aix1 + O_ + 3072];                      \
    } while (0)
    #define LOADB(DB, G, DST) do {                                             \
        constexpr int O_ = ((DB) * 2 + (G)) * 8192;                            \
        DST[0][0] = *(const bf16x8*)&Bs[bix0 + O_];                            \
        DST[0][1] = *(const bf16x8*)&Bs[bix1 + O_];                            \
        DST[1][0] = *(const bf16x8*)&Bs[bix0 + O_ + 1024];                     \
        DST[1][1] = *(const bf16x8*)&Bs[bix1 + O_ + 1024];                     \
    } while (0)
    // one K-tile, DB literal; stages ku1 = (KT+1)<<6, ku2 = (KT+2)<<6
    #define G256_TILE(DB, KT) do {                                             \
        const int ku1 = ((KT) + 1) << 6, ku2 = ((KT) + 2) << 6;                \
        LOADA(DB, 0); LOADB(DB, 0, bA);          /* ph0: quadrant (0,0) */     \
        stA(1, (DB) ^ 1, ku1);                                                 \
        BAR;                                                                   \
        mmac(0, 0, bA);                                                        \
        VMW(6); BAR;                                                           \
        LOADB(DB, 1, bB);                        /* ph1: quadrant (0,1) */     \
        stB(1, (DB) ^ 1, ku1);                                                 \
        BAR;                                                                   \
        mmac(0, 1, bB);                                                        \
        BAR;                                                                   \
        LOADA(DB, 1);                            /* ph2: quadrant (1,1) */     \
        stA(0, DB, ku2);                                                       \
        BAR;                                                                   \
        mmac(1, 1, bB);                                                        \
        BAR;                                                                   \
        stB(0, DB, ku2);                         /* ph3: quadrant (1,0) */     \
        BAR;                                                                   \
        mmac(1, 0, bA);                                                        \
        VMW(8); BAR;                                                           \
    } while (0)

    const int NT = K >> 6;                 // K-tiles of 64; NT even, >= 4
    // prologue: fill pipeline with 6 half-tile groups (FIFO):
    //   A0(0),B0(0),A1(0),B1(0),A0(1),B0(1); retire the first four.
    stA(0, 0, 0); stB(0, 0, 0); stA(1, 0, 0); stB(1, 0, 0);
    stA(0, 1, 64); stB(0, 1, 64);
    VMW(8);
    BAR;

    for (int kt = 0; kt + 4 <= NT; kt += 2) {
        G256_TILE(0, kt);
        G256_TILE(1, kt + 1);
    }
    {   // peeled tile NT-2 (db = 0 since NT even): only A1/B1(NT-1) to issue
        const int ku1 = (NT - 1) << 6;
        LOADA(0, 0); LOADB(0, 0, bA);
        stA(1, 1, ku1);
        BAR;
        mmac(0, 0, bA);
        VMW(6);
        BAR;
        LOADB(0, 1, bB);
        stB(1, 1, ku1);
        BAR;
        mmac(0, 1, bB);
        BAR;
        LOADA(0, 1);
        BAR;
        mmac(1, 1, bB);
        BAR;
        mmac(1, 0, bA);
        VMW(4);                           // retire A0(NT-1), B0(NT-1)
        BAR;
    }
    {   // peeled tile NT-1 (last, db = 1): no staging
        LOADA(1, 0); LOADB(1, 0, bA);
        BAR;
        mmac(0, 0, bA);
        VMW(0);                           // retire A1,B1(NT-1)
        BAR;
        LOADB(1, 1, bB);
        BAR;
        mmac(0, 1, bB);
        BAR;
        LOADA(1, 1);
        BAR;
        mmac(1, 1, bB);
        mmac(1, 0, bA);
    }
    #undef G256_TILE
    #undef LOADA
    #undef LOADB
    #undef BAR
    #undef VMW

    #pragma unroll
    for (int mi = 0; mi < 8; ++mi) {
        int row0 = bm + wm + mi * 16 + lq * 4;
        #pragma unroll
        for (int ni = 0; ni < 4; ++ni) {
            int col = bn + wn + ni * 16 + lr;
            float bv = bias[col];
            #pragma unroll
            for (int r = 0; r < 4; ++r) {
                float v = acc[mi][ni][r] + bv;
                size_t off = (size_t)(row0 + r) * N + col;
                if (MODE == 2) v = gelu_f(v);
                ((u16*)Cout)[off] = f2bf(v);
            }
        }
    }
}

// ---------------- Flash attention, band 512 + global-K tiles -----------------
__global__ __launch_bounds__(256) void attn_kernel(const u16* __restrict__ qh,
                                                   const u16* __restrict__ kh,
                                                   const u16* __restrict__ vt,
                                                   const unsigned long long* __restrict__ kmask,
                                                   u16* __restrict__ ctx) {
    const int qt = blockIdx.x, bh = blockIdx.y;
    const int b = bh >> 4, h = bh & 15;
    const int t = threadIdx.x, wv = t >> 6, lane = t & 63;
    const int lr = lane & 15, lq = lane >> 4;
    const int q0 = qt * 64;

    __shared__ __align__(16) u16 Qs[64 * 64];
    __shared__ __align__(16) u16 Ks[2][64 * 64];
    __shared__ __align__(16) u16 Vs[2][64 * 64];
    __shared__ __align__(16) u16 Ps[64 * 64];

    const u16* qbase = qh + ((size_t)bh * SS) * DH;
    const u16* kbase = kh + ((size_t)bh * SS) * DH;
    const u16* vbase = vt + ((size_t)bh * DH) * SS;

    #pragma unroll
    for (int p = 0; p < 2; ++p) {
        int c = p * 256 + t; int r = c >> 3, sl = c & 7;
        gld_lds16(qbase + (size_t)(q0 + r) * DH + ((sl ^ (r & 7)) * 8),
                  Qs + (size_t)(p * 256 + wv * 64) * 8);
    }

    float sum_part[4] = {0.f, 0.f, 0.f, 0.f};
    f32x4 acc_o[4] = {};

    const int lim = qt - 8;        // kt >= lim always included (band)
    int cur = 0;
    while (cur < lim && kmask[cur] == 0ull) ++cur;
    {
        int k0 = cur * 64;
        #pragma unroll
        for (int p = 0; p < 2; ++p) {
            int c = p * 256 + t; int r = c >> 3; int gc = ((c & 7) ^ (r & 7)) * 8;
            gld_lds16(kbase + (size_t)(k0 + r) * DH + gc, Ks[0] + (size_t)(p * 256 + wv * 64) * 8);
            gld_lds16(vbase + (size_t)r * SS + k0 + gc,  Vs[0] + (size_t)(p * 256 + wv * 64) * 8);
        }
    }
    int pb = 0;
    while (cur >= 0) {
        int nxt = cur + 1;
        while (nxt < lim && kmask[nxt] == 0ull) ++nxt;
        if (nxt > qt) nxt = -1;
        __syncthreads();                       // buf pb ready for all waves
        if (nxt >= 0) {
            int k0n = nxt * 64;
            #pragma unroll
            for (int p = 0; p < 2; ++p) {
                int c = p * 256 + t; int r = c >> 3; int gc = ((c & 7) ^ (r & 7)) * 8;
                gld_lds16(kbase + (size_t)(k0n + r) * DH + gc, Ks[pb ^ 1] + (size_t)(p * 256 + wv * 64) * 8);
                gld_lds16(vbase + (size_t)r * SS + k0n + gc,  Vs[pb ^ 1] + (size_t)(p * 256 + wv * 64) * 8);
            }
        }
        const u16* Kt = Ks[pb];
        const u16* Vt = Vs[pb];
        const int k0 = cur * 64;

        f32x4 s_acc[4] = {};
        #pragma unroll
        for (int ks = 0; ks < 2; ++ks) {
            const int arow = wv * 16 + lr;
            bf16x8 af = *(const bf16x8*)&Qs[arow * 64 + (((ks * 4 + lq) ^ (arow & 7)) * 8)];
            #pragma unroll
            for (int ni = 0; ni < 4; ++ni) {
                const int brow = ni * 16 + lr;
                bf16x8 bfr = *(const bf16x8*)&Kt[brow * 64 + (((ks * 4 + lq) ^ (brow & 7)) * 8)];
                s_acc[ni] = __builtin_amdgcn_mfma_f32_16x16x32_bf16(af, bfr, s_acc[ni], 0, 0, 0);
            }
        }
        float sv[4][4];
        if (cur >= qt - 7 && cur != qt) {                    // FULL
            #pragma unroll
            for (int ni = 0; ni < 4; ++ni)
                #pragma unroll
                for (int r = 0; r < 4; ++r) sv[ni][r] = __expf(s_acc[ni][r]);
        } else if (cur == qt) {                              // DIAG
            #pragma unroll
            for (int ni = 0; ni < 4; ++ni) {
                int j = ni * 16 + lr;
                #pragma unroll
                for (int r = 0; r < 4; ++r) {
                    int i = wv * 16 + lq * 4 + r;
                    float p = __expf(s_acc[ni][r]);
                    sv[ni][r] = (j <= i) ? p : 0.f;
                }
            }
        } else {                                             // MASKED
            unsigned long long cm = kmask[cur];
            #pragma unroll
            for (int ni = 0; ni < 4; ++ni) {
                int j = k0 + ni * 16 + lr;
                bool gj = (cm >> (ni * 16 + lr)) & 1ull;
                #pragma unroll
                for (int r = 0; r < 4; ++r) {
                    int i = q0 + wv * 16 + lq * 4 + r;
                    bool ok = ((i - j) < 512) | gj;
                    float p = __expf(s_acc[ni][r]);
                    sv[ni][r] = ok ? p : 0.f;
                }
            }
        }
        #pragma unroll
        for (int ni = 0; ni < 4; ++ni) {
            int col = ni * 16 + lr;
            #pragma unroll
            for (int r = 0; r < 4; ++r) {
                int row = wv * 16 + lq * 4 + r;
                sum_part[r] += sv[ni][r];
                Ps[row * 64 + (((col >> 3) ^ (row & 7)) * 8) + (col & 7)] = f2bf(sv[ni][r]);
            }
        }
        #pragma unroll
        for (int ks = 0; ks < 2; ++ks) {
            const int arow = wv * 16 + lr;
            bf16x8 af = *(const bf16x8*)&Ps[arow * 64 + (((ks * 4 + lq) ^ (arow & 7)) * 8)];
            #pragma unroll
            for (int ni = 0; ni < 4; ++ni) {
                const int brow = ni * 16 + lr;
                bf16x8 bfr = *(const bf16x8*)&Vt[brow * 64 + (((ks * 4 + lq) ^ (brow & 7)) * 8)];
                acc_o[ni] = __builtin_amdgcn_mfma_f32_16x16x32_bf16(af, bfr, acc_o[ni], 0, 0, 0);
            }
        }
        cur = nxt; pb ^= 1;
    }
    float inv_l[4];
    #pragma unroll
    for (int r = 0; r < 4; ++r) {
        float ls = sum_part[r];
        #pragma unroll
        for (int m = 1; m < 16; m <<= 1) ls += __shfl_xor(ls, m, 16);
        inv_l[r] = 1.f / ls;
    }
    u16* obase = ctx + ((size_t)b * SS) * DM + h * DH;
    #pragma unroll
    for (int ni = 0; ni < 4; ++ni)
        #pragma unroll
        for (int r = 0; r < 4; ++r) {
            int i = q0 + wv * 16 + lq * 4 + r;
            obase[(size_t)i * DM + ni * 16 + lr] = f2bf(acc_o[ni][r] * inv_l[r]);
        }
}

// ---------------- Global-row fixup: lane = key, zero in-loop cross-lane ops --
__global__ __launch_bounds__(256) void attn_fix_kernel(const u16* __restrict__ qh,
                                                       const u16* __restrict__ kh,
                                                       const u16* __restrict__ qkv,
                                                       const int* __restrict__ gti,
                                                       u16* __restrict__ ctx) {
    const int gidx = blockIdx.x, bh = blockIdx.y;
    const int b = bh >> 4, h = bh & 15;
    const int t = threadIdx.x, wv = t >> 6, lane = t & 63;
    const int i = gti[gidx];

    __shared__ float qsh[64];
    if (t < 64) qsh[t] = bf2f(qh[((size_t)bh * SS + i) * DH + t]);   // RoPE'd, prescaled
    __syncthreads();
    float qreg[64];
    #pragma unroll
    for (int c = 0; c < 16; ++c) {
        float4 qv = ((const float4*)qsh)[c];   // broadcast
        qreg[c * 4 + 0] = qv.x; qreg[c * 4 + 1] = qv.y;
        qreg[c * 4 + 2] = qv.z; qreg[c * 4 + 3] = qv.w;
    }

    const u16* kb = kh + (size_t)bh * SS * DH;
    const u16* vb = qkv + (size_t)b * SS * 3072 + 2048 + h * DH;

    float Oacc[64];
    #pragma unroll
    for (int d = 0; d < 64; ++d) Oacc[d] = 0.f;
    float lacc = 0.f;

    for (int j0 = wv * 64; j0 <= i; j0 += 256) {
        const int j = j0 + lane;
        const bool valid = (j <= i);
        const int jc = valid ? j : i;
        const s16x8* krow = (const s16x8*)(kb + (size_t)jc * DH);
        float part[8];
        #pragma unroll
        for (int c = 0; c < 8; ++c) {
            s16x8 kv = krow[c];
            float p0 = 0.f;
            #pragma unroll
            for (int e = 0; e < 8; ++e) p0 += qreg[c * 8 + e] * bf2f((u16)kv[e]);
            part[c] = p0;
        }
        float s = ((part[0] + part[1]) + (part[2] + part[3])) +
                  ((part[4] + part[5]) + (part[6] + part[7]));
        const float p = valid ? __expf(s) : 0.f;
        lacc += p;
        const s16x8* vrow = (const s16x8*)(vb + (size_t)jc * 3072);
        #pragma unroll
        for (int c = 0; c < 8; ++c) {
            s16x8 vv = vrow[c];
            #pragma unroll
            for (int e = 0; e < 8; ++e) Oacc[c * 8 + e] += p * bf2f((u16)vv[e]);
        }
    }
    #pragma unroll
    for (int m = 1; m < 64; m <<= 1) {
        lacc += __shfl_xor(lacc, m);
        #pragma unroll
        for (int d = 0; d < 64; ++d) Oacc[d] += __shfl_xor(Oacc[d], m);
    }
    float out = 0.f;
    #pragma unroll
    for (int d = 0; d < 64; ++d) out = (lane == d) ? Oacc[d] : out;
    __shared__ float osum[4][64];
    __shared__ float lsum[4];
    osum[wv][lane] = out;
    if (lane == 0) lsum[wv] = lacc;
    __syncthreads();
    if (wv == 0) {
        float ot = osum[0][lane] + osum[1][lane] + osum[2][lane] + osum[3][lane];
        float lt = lsum[0] + lsum[1] + lsum[2] + lsum[3];
        ctx[((size_t)b * SS + i) * DM + h * DH + lane] = f2bf(ot / lt);
    }
}

extern "C" void kernel_launch(void* const* d_in, const int* in_sizes, int n_in,
                              void* d_out, int out_size, void* d_ws, size_t ws_size,
                              hipStream_t stream) {
    (void)in_sizes; (void)n_in; (void)out_size; (void)ws_size;
    const float* hidden = (const float*)d_in[0];
    const float* ln1_g  = (const float*)d_in[1];
    const float* ln1_b  = (const float*)d_in[2];
    const float* wq = (const float*)d_in[3];  const float* bq = (const float*)d_in[4];
    const float* wk = (const float*)d_in[5];  const float* bk = (const float*)d_in[6];
    const float* wv = (const float*)d_in[7];  const float* bv = (const float*)d_in[8];
    const float* wo = (const float*)d_in[9];  const float* bo = (const float*)d_in[10];
    const float* ln2_g = (const float*)d_in[11];
    const float* ln2_b = (const float*)d_in[12];
    const float* w1 = (const float*)d_in[13]; const float* b1 = (const float*)d_in[14];
    const float* w2 = (const float*)d_in[15]; const float* b2 = (const float*)d_in[16];
    const int*  gti = (const int*)d_in[17];

    char* ws = (char*)d_ws;
    const size_t MB = 1u << 20;
    u16* wqt  = (u16*)(ws + 0 * MB);    // [3072][1024] contiguous (wq|wk|wv transposed)
    u16* wkt  = (u16*)(ws + 2 * MB);
    u16* wvt  = (u16*)(ws + 4 * MB);
    u16* wot  = (u16*)(ws + 6 * MB);
    u16* w1t  = (u16*)(ws + 8 * MB);    // [4096][1024]
    u16* w2t  = (u16*)(ws + 16 * MB);   // [1024][4096]
    u16* xb   = (u16*)(ws + 24 * MB);   // ln1 out; reused as ctx after QKV
    u16* ctx  = xb;
    u16* qkv  = (u16*)(ws + 32 * MB);   // [4096][3072] bf16, 24MB (32..56)
    u16* qhb  = (u16*)(ws + 56 * MB);
    u16* khb  = (u16*)(ws + 64 * MB);
    u16* vtb  = (u16*)(ws + 72 * MB);
    float* hb = (float*)(ws + 80 * MB); // fp32 residual h, 16MB
    u16* act  = (u16*)(ws + 32 * MB);   // 32MB (32..64): qkv+qhb dead after fixup
    u16* yb   = (u16*)(ws + 64 * MB);   // reuses khb (dead after fixup)
    unsigned long long* kmask = (unsigned long long*)(ws + 96 * MB);
    float* bias3 = (float*)(ws + 96 * MB + 8192);

    wtrans4_kernel<<<dim3(16, 16, 4), 256, 0, stream>>>(wq, wk, wv, wo, wqt, wkt, wvt, wot);
    wtrans_kernel<<<dim3(64, 16), 256, 0, stream>>>(w1, w1t, DM, DFF);
    wtrans_kernel<<<dim3(16, 64), 256, 0, stream>>>(w2, w2t, DFF, DM);
    build_aux<<<1, 256, 0, stream>>>(gti, kmask, bq, bk, bv, bias3);

    ln_kernel<false><<<NB * SS, 256, 0, stream>>>(hidden, ln1_g, ln1_b, xb, nullptr, nullptr);

    // fused QKV: A[4096x1024] * [wq|wk|wv]^T -> qkv[4096x3072]  (8-phase, free-sched)
    gemm256<0, 1><<<dim3(3072 / 256, (NB * SS) / 256), 512, 0, stream>>>(
        xb, wqt, bias3, qkv, NB * SS, 3072, DM, DM);

    rope_kernel<<<(NB * NH * SS * 32) / 256, 256, 0, stream>>>(qkv, qhb, khb);
    vtrans_kernel<<<dim3(SS / 64, NB * NH), 256, 0, stream>>>(qkv, vtb);

    attn_kernel<<<dim3(SS / 64, NB * NH), 256, 0, stream>>>(qhb, khb, vtb, kmask, ctx);
    attn_fix_kernel<<<dim3(8, NB * NH), 256, 0, stream>>>(qhb, khb, qkv, gti, ctx);

    gemm_bt<1, 1><<<dim3(8, 32), 256, 0, stream>>>(ctx, wot, bo, hidden, hb, NB * SS, DM, DM, DM);
    // ln2 + init d_out = h + b2 (accumulation target for split-K w2)
    ln_kernel<true><<<NB * SS, 256, 0, stream>>>(hb, ln2_g, ln2_b, yb, b2, (float*)d_out);
    // MLP GEMM1: gelu(y @ w1 + b1) -> act  (8-phase free-sched, 256 blocks = 1/CU)
    gemm256<2, 1><<<dim3(DFF / 256, (NB * SS) / 256), 512, 0, stream>>>(
        yb, w1t, b1, act, NB * SS, DFF, DM, DM);
    // MLP GEMM2: split-K=2 (512 blocks): d_out += act * w2t^T  (XCD-remapped)
    gemm_bt<3, 1><<<dim3(8, 32, 2), 256, 0, stream>>>(act, w2t, nullptr, nullptr, d_out, NB * SS, DM, DFF / 2, DFF);
}

// Round 10
// 384.469 us; speedup vs baseline: 1.3199x; 1.0046x over previous
//
#include <hip/hip_runtime.h>

typedef unsigned short u16;
typedef __bf16 bf16x8 __attribute__((ext_vector_type(8)));
typedef short s16x8 __attribute__((ext_vector_type(8)));
typedef float f32x4 __attribute__((ext_vector_type(4)));

#define NB 2
#define SS 2048
#define DM 1024
#define NH 16
#define DH 64
#define DFF 4096

__device__ __forceinline__ u16 f2bf(float f) {
    unsigned u = __float_as_uint(f);
    u += 0x7fff + ((u >> 16) & 1);   // RNE
    return (u16)(u >> 16);
}
__device__ __forceinline__ float bf2f(u16 h) {
    return __uint_as_float(((unsigned)h) << 16);
}
// async global->LDS, 16B per lane. LDS dest must be wave-uniform base + lane*16.
__device__ __forceinline__ void gld_lds16(const void* g, void* l) {
    __builtin_amdgcn_global_load_lds(
        (const __attribute__((address_space(1))) unsigned int*)(size_t)g,
        (__attribute__((address_space(3))) unsigned int*)(unsigned)(size_t)l,
        16, 0, 0);
}
__device__ __forceinline__ float gelu_f(float x) {
    return 0.5f * x * (1.f + erff(x * 0.70710678118654752f));
}

// ---------------- weight convert + transpose: w[K][N] fp32 -> wt[N][K] bf16 ----
__global__ void wtrans_kernel(const float* __restrict__ w, u16* __restrict__ wt,
                              int K, int N) {
    __shared__ unsigned tl[64][65];
    int n0 = blockIdx.x * 64, k0 = blockIdx.y * 64, t = threadIdx.x;
    for (int it = 0; it < 16; ++it) {
        int e = it * 256 + t; int r = e >> 6, c = e & 63;       // r: k, c: n
        tl[r][c] = f2bf(w[(size_t)(k0 + r) * N + n0 + c]);
    }
    __syncthreads();
    for (int it = 0; it < 16; ++it) {
        int e = it * 256 + t; int r = e >> 6, c = e & 63;       // r: n, c: k
        wt[(size_t)(n0 + r) * K + k0 + c] = (u16)tl[c][r];
    }
}

// batched version for the four 1024x1024 projection weights
__global__ void wtrans4_kernel(const float* __restrict__ a, const float* __restrict__ b,
                               const float* __restrict__ c, const float* __restrict__ d,
                               u16* __restrict__ oa, u16* __restrict__ ob,
                               u16* __restrict__ oc, u16* __restrict__ od) {
    __shared__ unsigned tl[64][65];
    const float* w; u16* wt;
    switch (blockIdx.z) {
        case 0: w = a; wt = oa; break;
        case 1: w = b; wt = ob; break;
        case 2: w = c; wt = oc; break;
        default: w = d; wt = od; break;
    }
    int n0 = blockIdx.x * 64, k0 = blockIdx.y * 64, t = threadIdx.x;
    for (int it = 0; it < 16; ++it) {
        int e = it * 256 + t; int r = e >> 6, cc = e & 63;
        tl[r][cc] = f2bf(w[(size_t)(k0 + r) * DM + n0 + cc]);
    }
    __syncthreads();
    for (int it = 0; it < 16; ++it) {
        int e = it * 256 + t; int r = e >> 6, cc = e & 63;
        wt[(size_t)(n0 + r) * DM + k0 + cc] = (u16)tl[cc][r];
    }
}

// ---------------- aux: per-k-tile global bitmasks + concat QKV bias ----------
__global__ void build_aux(const int* __restrict__ gti, unsigned long long* __restrict__ kmask,
                          const float* __restrict__ bq, const float* __restrict__ bk,
                          const float* __restrict__ bv, float* __restrict__ bias3) {
    int t = threadIdx.x;
    if (t < 32) {
        unsigned long long m = 0ull;
        #pragma unroll
        for (int i = 0; i < 8; ++i) {
            int g = gti[i];
            if ((g >> 6) == t) m |= 1ull << (g & 63);
        }
        kmask[t] = m;
    }
    for (int i = t; i < 1024; i += 256) {
        bias3[i] = bq[i]; bias3[1024 + i] = bk[i]; bias3[2048 + i] = bv[i];
    }
}

// ---------------- LayerNorm: fp32 in -> bf16 out; INIT also writes iout=x+ib --
template <bool INIT>
__global__ __launch_bounds__(256) void ln_kernel(const float* __restrict__ x,
                                                 const float* __restrict__ g,
                                                 const float* __restrict__ b,
                                                 u16* __restrict__ out,
                                                 const float* __restrict__ ib,
                                                 float* __restrict__ iout) {
    int row = blockIdx.x, t = threadIdx.x;
    const float4 v = ((const float4*)(x + (size_t)row * DM))[t];
    float s  = v.x + v.y + v.z + v.w;
    float sq = v.x * v.x + v.y * v.y + v.z * v.z + v.w * v.w;
    #pragma unroll
    for (int m = 1; m < 64; m <<= 1) { s += __shfl_xor(s, m); sq += __shfl_xor(sq, m); }
    __shared__ float ss[4], ssq[4];
    int wv = t >> 6, lane = t & 63;
    if (lane == 0) { ss[wv] = s; ssq[wv] = sq; }
    __syncthreads();
    s  = ss[0] + ss[1] + ss[2] + ss[3];
    sq = ssq[0] + ssq[1] + ssq[2] + ssq[3];
    float mean = s * (1.f / DM);
    float var  = sq * (1.f / DM) - mean * mean;
    float rs   = rsqrtf(var + 1e-5f);
    float4 gg = ((const float4*)g)[t];
    float4 bb = ((const float4*)b)[t];
    ushort4 o;
    o.x = f2bf((v.x - mean) * rs * gg.x + bb.x);
    o.y = f2bf((v.y - mean) * rs * gg.y + bb.y);
    o.z = f2bf((v.z - mean) * rs * gg.z + bb.z);
    o.w = f2bf((v.w - mean) * rs * gg.w + bb.w);
    ((ushort4*)(out + (size_t)row * DM))[t] = o;
    if (INIT) {
        float4 b2 = ((const float4*)ib)[t];
        float4 iv; iv.x = v.x + b2.x; iv.y = v.y + b2.y; iv.z = v.z + b2.z; iv.w = v.w + b2.w;
        ((float4*)(iout + (size_t)row * DM))[t] = iv;
    }
}

// ---------------- RoPE: qkv bf16 [B,S,3072] -> head-major bf16 [B,H,S,Dh] ----
// Q is prescaled by 1/sqrt(Dh)=0.125 so attention needs no score scaling.
__global__ __launch_bounds__(256) void rope_kernel(const u16* __restrict__ qkv,
                                                   u16* __restrict__ qh,
                                                   u16* __restrict__ kh) {
    int idx = blockIdx.x * 256 + threadIdx.x;   // B*H*S*32 threads
    int d = idx & 31;
    int s = (idx >> 5) & (SS - 1);
    int h = (idx >> 16) & (NH - 1);
    int b = idx >> 20;
    size_t src = ((size_t)(b * SS + s)) * 3072 + h * DH + d;
    size_t dst = ((size_t)((b * NH + h) * SS + s)) * DH + d;
    float inv = powf(10000.f, -(float)d * (1.f / 32.f));
    float ang = (float)s * inv;
    float sn, cs;
    sincosf(ang, &sn, &cs);
    const float QSC = 0.125f;
    float x1 = bf2f(qkv[src]), x2 = bf2f(qkv[src + 32]);
    qh[dst]      = f2bf((x1 * cs - x2 * sn) * QSC);
    qh[dst + 32] = f2bf((x2 * cs + x1 * sn) * QSC);
    x1 = bf2f(qkv[src + 1024]); x2 = bf2f(qkv[src + 1024 + 32]);
    kh[dst]      = f2bf(x1 * cs - x2 * sn);
    kh[dst + 32] = f2bf(x2 * cs + x1 * sn);
}

// ---------------- V transpose: qkv [B,S,3072] (v at +2048) -> [B,H,Dh,S] -----
__global__ __launch_bounds__(256) void vtrans_kernel(const u16* __restrict__ qkv,
                                                     u16* __restrict__ vt) {
    __shared__ unsigned tile[64][65];
    int st = blockIdx.x, bh = blockIdx.y;
    int b = bh >> 4, h = bh & 15, t = threadIdx.x;
    const u16* src = qkv + ((size_t)b * SS + st * 64) * 3072 + 2048 + h * DH;
    for (int it = 0; it < 16; ++it) {
        int e = it * 256 + t; int r = e >> 6, c = e & 63;       // r: s, c: d
        tile[r][c] = src[(size_t)r * 3072 + c];
    }
    __syncthreads();
    u16* dst = vt + ((size_t)bh * DH) * SS + st * 64;
    for (int it = 0; it < 16; ++it) {
        int e = it * 256 + t; int d = e >> 6, s = e & 63;
        dst[(size_t)d * SS + s] = (u16)tile[s][d];
    }
}

// XCD-aware remap: dispatch slot s -> (bn, bm, bz) so that slots on the same
// XCD (s & 7 under round-robin) share A-row panels (same bm chunk).
// Requires gridDim.y % 8 == 0.
__device__ __forceinline__ void xcd_remap(int& bn, int& bm, int& bz) {
    int s = blockIdx.x + gridDim.x * (blockIdx.y + gridDim.y * blockIdx.z);
    int q = gridDim.y >> 3;                  // bm chunk per XCD
    int xcd = s & 7, lin = s >> 3;
    bm = xcd * q + (lin % q);
    int rest = lin / q;
    bn = rest % gridDim.x;
    bz = rest / gridDim.x;
}

// ---------------- GEMM (legacy 128x128): C[M,N] = A[M,K](bf16) * Bt[N,K]^T ---
// MODE 1: +bias+res -> fp32 (Wo). MODE 3: split-K partial, atomicAdd fp32.
template <int MODE, int REMAP>
__global__ __launch_bounds__(256) void gemm_bt(const u16* __restrict__ A,
                                               const u16* __restrict__ Bt,
                                               const float* __restrict__ bias,
                                               const float* __restrict__ res,
                                               void* __restrict__ Cout,
                                               int M, int N, int K, int ldk) {
    int bnb = blockIdx.x, bmb = blockIdx.y, bzb = blockIdx.z;
    if (REMAP) xcd_remap(bnb, bmb, bzb);
    const int bm = bmb * 128, bn = bnb * 128;
    const int koff = bzb * K;
    const int t = threadIdx.x, wv = t >> 6, lane = t & 63;
    const int lr = lane & 15, lq = lane >> 4;
    const int wm = (wv >> 1) * 64, wn = (wv & 1) * 64;
    __shared__ __align__(16) u16 As[2][128 * 64];   // [m][k] swizzled, 16 KB each
    __shared__ __align__(16) u16 Bs[2][128 * 64];   // [n][k] swizzled
    f32x4 acc[4][4] = {};

    auto stage = [&](int kb, int buf) {
        #pragma unroll
        for (int p = 0; p < 4; ++p) {
            int c = p * 256 + t;                 // chunk id 0..1023, 16B each
            int r = c >> 3;                      // row 0..127
            int gc = ((c & 7) ^ (r & 7)) * 8;    // swizzled source column
            gld_lds16(A + (size_t)(bm + r) * ldk + kb + gc,
                      As[buf] + (size_t)(p * 256 + wv * 64) * 8);
            gld_lds16(Bt + (size_t)(bn + r) * ldk + kb + gc,
                      Bs[buf] + (size_t)(p * 256 + wv * 64) * 8);
        }
    };

    stage(koff, 0);
    int pb = 0;
    for (int k0 = 0; k0 < K; k0 += 64) {
        __syncthreads();                       // buf pb complete for all waves
        if (k0 + 64 < K) stage(koff + k0 + 64, pb ^ 1);
        const u16* Ac = As[pb];
        const u16* Bc = Bs[pb];
        #pragma unroll
        for (int ks = 0; ks < 2; ++ks) {
            bf16x8 af[4], bfr[4];
            #pragma unroll
            for (int mi = 0; mi < 4; ++mi) {
                int row = wm + mi * 16 + lr;
                af[mi] = *(const bf16x8*)&Ac[row * 64 + (((ks * 4 + lq) ^ (row & 7)) * 8)];
            }
            #pragma unroll
            for (int ni = 0; ni < 4; ++ni) {
                int row = wn + ni * 16 + lr;
                bfr[ni] = *(const bf16x8*)&Bc[row * 64 + (((ks * 4 + lq) ^ (row & 7)) * 8)];
            }
            #pragma unroll
            for (int mi = 0; mi < 4; ++mi)
                #pragma unroll
                for (int ni = 0; ni < 4; ++ni)
                    acc[mi][ni] = __builtin_amdgcn_mfma_f32_16x16x32_bf16(af[mi], bfr[ni], acc[mi][ni], 0, 0, 0);
        }
        pb ^= 1;
    }
    #pragma unroll
    for (int mi = 0; mi < 4; ++mi) {
        int row0 = bm + wm + mi * 16 + lq * 4;
        #pragma unroll
        for (int ni = 0; ni < 4; ++ni) {
            int col = bn + wn + ni * 16 + lr;
            float bv = (MODE == 3) ? 0.f : bias[col];
            #pragma unroll
            for (int r = 0; r < 4; ++r) {
                float v = acc[mi][ni][r] + bv;
                size_t off = (size_t)(row0 + r) * N + col;
                if (MODE == 1) v += res[off];
                if (MODE == 2) v = gelu_f(v);
                if (MODE == 0 || MODE == 2) ((u16*)Cout)[off] = f2bf(v);
                else if (MODE == 1)         ((float*)Cout)[off] = v;
                else                        atomicAdd((float*)Cout + off, v);
            }
        }
    }
}

// ---------------- GEMM 256x256: 8-phase, deep counted-vmcnt, imm-offset LDS --
// Schedule as round-3/4 EXCEPT: no lgkmcnt(0) drain and no sched_barrier(0)
// per phase. All LDS reads are compiler-visible C++ loads, so the compiler
// emits fine-grained counted lgkmcnt waits before each dependent MFMA and is
// free to overlap LDS-return latency with MFMA issue (m141 lesson: pinning
// the order defeats the scheduler). Correctness: each phase's ds_reads are
// consumed by that phase's MFMAs (so they complete before the end-of-phase
// barrier), and cross-wave staging WAR/RAW is ordered by the barriers + the
// unchanged counted-vmcnt ledger:
//   ph0 stages A1(kt+1); ph1: B1(kt+1); ph2: A0(kt+2); ph3: B0(kt+2);
//   end-ph0: vmcnt(6) retires through B1(kt); end-ph3: vmcnt(8) retires
//   A0(kt+1), B0(kt+1). Never drained to 0 in the main loop.
// MODE 0: +bias -> bf16 ; MODE 2: gelu(+bias) -> bf16.  Requires NT even >= 4.
template <int MODE, int REMAP>
__global__ __launch_bounds__(512, 2) void gemm256(const u16* __restrict__ A,
                                                  const u16* __restrict__ Bt,
                                                  const float* __restrict__ bias,
                                                  void* __restrict__ Cout,
                                                  int M, int N, int K, int ldk) {
    int bnb = blockIdx.x, bmb = blockIdx.y, bzb = blockIdx.z;
    if (REMAP) xcd_remap(bnb, bmb, bzb);
    const int bm = bmb * 256, bn = bnb * 256;
    const int t = threadIdx.x, wv = t >> 6, lane = t & 63;
    const int lr = lane & 15, lq = lane >> 4;
    const int wm = (wv >> 2) * 128, wn = (wv & 3) * 64;
    const int awb = (wv >> 2) * 64;          // A group-local wave base
    const int bwb = (wv & 3) * 32;           // B group-local wave base
    __shared__ __align__(16) u16 As[2 * 2 * 128 * 64];   // [db][grp][128][64]
    __shared__ __align__(16) u16 Bs[2 * 2 * 128 * 64];
    f32x4 acc[8][4] = {};
    bf16x8 aA[4][2], bA[2][2], bB[2][2];

    // 4 per-lane LDS base indices (u16 units); everything else is an immediate.
    const int aix0 = (awb + lr) * 64 + ((lq ^ (lr & 7)) * 8);
    const int aix1 = aix0 ^ 32;              // ks=1: slot^4 -> elem^32
    const int bix0 = (bwb + lr) * 64 + ((lq ^ (lr & 7)) * 8);
    const int bix1 = bix0 ^ 32;

    // per-thread pre-swizzled staging source pointers (2 loads per half-tile)
    const u16 *pAsrc[2][2], *pBsrc[2][2];
    #pragma unroll
    for (int g = 0; g < 2; ++g)
        #pragma unroll
        for (int p = 0; p < 2; ++p) {
            int c = p * 512 + t;                         // chunk 0..1023
            int glr = c >> 3, sl = c & 7;                // group-local row, slot
            int sc = (sl ^ (glr & 7)) * 8;               // pre-swizzled col
            int grA = (glr & 63) + g * 64 + ((glr >> 6) << 7);
            int grB = (glr & 31) + g * 32 + ((glr >> 5) << 6);
            pAsrc[g][p] = A  + (size_t)(bm + grA) * ldk + sc;
            pBsrc[g][p] = Bt + (size_t)(bn + grB) * ldk + sc;
        }
    auto stA = [&](int g, int db, int ku) {
        #pragma unroll
        for (int p = 0; p < 2; ++p)
            gld_lds16(pAsrc[g][p] + ku, As + (size_t)(db * 2 + g) * 8192
                                           + (size_t)(p * 512 + wv * 64) * 8);
    };
    auto stB = [&](int g, int db, int ku) {
        #pragma unroll
        for (int p = 0; p < 2; ++p)
            gld_lds16(pBsrc[g][p] + ku, Bs + (size_t)(db * 2 + g) * 8192
                                           + (size_t)(p * 512 + wv * 64) * 8);
    };
    auto mmac = [&](int qm, int qn, bf16x8 (&bb)[2][2]) {      // 16 MFMA
        __builtin_amdgcn_s_setprio(1);
        #pragma unroll
        for (int mi2 = 0; mi2 < 4; ++mi2)
            #pragma unroll
            for (int ni2 = 0; ni2 < 2; ++ni2)
                #pragma unroll
                for (int ks = 0; ks < 2; ++ks)
                    acc[qm * 4 + mi2][qn * 2 + ni2] =
                        __builtin_amdgcn_mfma_f32_16x16x32_bf16(
                            aA[mi2][ks], bb[ni2][ks], acc[qm * 4 + mi2][qn * 2 + ni2], 0, 0, 0);
        __builtin_amdgcn_s_setprio(0);
    };
    #define BAR       __builtin_amdgcn_s_barrier()
    #define VMW(n)    asm volatile("s_waitcnt vmcnt(" #n ")" ::: "memory")
    // all-immediate LDS fragment loads (DB, G literals at every call site)
    #define LOADA(DB, G) do {                                                  \
        constexpr int O_ = ((DB) * 2 + (G)) * 8192;                            \
        aA[0][0] = *(const bf16x8*)&As[aix0 + O_];                             \
        aA[0][1] = *(const bf16x8*)&As[aix1 + O_];                             \
        aA[1][0] = *(const bf16x8*)&As[aix0 + O_ + 1024];                      \
        aA[1][1] = *(const bf16x8*)&As[aix1 + O_ + 1024];                      \
        aA[2][0] = *(const bf16x8*)&As[aix0 + O_ + 2048];                      \
        aA[2][1] = *(const bf16x8*)&As[aix1 + O_ + 2048];                      \
        aA[3][0] = *(const bf16x8*)&As[aix0 + O_ + 3072];                      \
        aA[3][1] = *(const bf16x8*)&As[aix1 + O_ + 3072];                      \
    } while (0)
    #define LOADB(DB, G, DST) do {                                             \
        constexpr int O_ = ((DB) * 2 + (G)) * 8192;                            \
        DST[0][0] = *(const bf16x8*)&Bs[bix0 + O_];                            \
        DST[0][1] = *(const bf16x8*)&Bs[bix1 + O_];                            \
        DST[1][0] = *(const bf16x8*)&Bs[bix0 + O_ + 1024];                     \
        DST[1][1] = *(const bf16x8*)&Bs[bix1 + O_ + 1024];                     \
    } while (0)
    // one K-tile, DB literal; stages ku1 = (KT+1)<<6, ku2 = (KT+2)<<6
    #define G256_TILE(DB, KT) do {                                             \
        const int ku1 = ((KT) + 1) << 6, ku2 = ((KT) + 2) << 6;                \
        LOADA(DB, 0); LOADB(DB, 0, bA);          /* ph0: quadrant (0,0) */     \
        stA(1, (DB) ^ 1, ku1);                                                 \
        BAR;                                                                   \
        mmac(0, 0, bA);                                                        \
        VMW(6); BAR;                                                           \
        LOADB(DB, 1, bB);                        /* ph1: quadrant (0,1) */     \
        stB(1, (DB) ^ 1, ku1);                                                 \
        BAR;                                                                   \
        mmac(0, 1, bB);                                                        \
        BAR;                                                                   \
        LOADA(DB, 1);                            /* ph2: quadrant (1,1) */     \
        stA(0, DB, ku2);                                                       \
        BAR;                                                                   \
        mmac(1, 1, bB);                                                        \
        BAR;                                                                   \
        stB(0, DB, ku2);                         /* ph3: quadrant (1,0) */     \
        BAR;                                                                   \
        mmac(1, 0, bA);                                                        \
        VMW(8); BAR;                                                           \
    } while (0)

    const int NT = K >> 6;                 // K-tiles of 64; NT even, >= 4
    // prologue: fill pipeline with 6 half-tile groups (FIFO):
    //   A0(0),B0(0),A1(0),B1(0),A0(1),B0(1); retire the first four.
    stA(0, 0, 0); stB(0, 0, 0); stA(1, 0, 0); stB(1, 0, 0);
    stA(0, 1, 64); stB(0, 1, 64);
    VMW(8);
    BAR;

    for (int kt = 0; kt + 4 <= NT; kt += 2) {
        G256_TILE(0, kt);
        G256_TILE(1, kt + 1);
    }
    {   // peeled tile NT-2 (db = 0 since NT even): only A1/B1(NT-1) to issue
        const int ku1 = (NT - 1) << 6;
        LOADA(0, 0); LOADB(0, 0, bA);
        stA(1, 1, ku1);
        BAR;
        mmac(0, 0, bA);
        VMW(6);
        BAR;
        LOADB(0, 1, bB);
        stB(1, 1, ku1);
        BAR;
        mmac(0, 1, bB);
        BAR;
        LOADA(0, 1);
        BAR;
        mmac(1, 1, bB);
        BAR;
        mmac(1, 0, bA);
        VMW(4);                           // retire A0(NT-1), B0(NT-1)
        BAR;
    }
    {   // peeled tile NT-1 (last, db = 1): no staging
        LOADA(1, 0); LOADB(1, 0, bA);
        BAR;
        mmac(0, 0, bA);
        VMW(0);                           // retire A1,B1(NT-1)
        BAR;
        LOADB(1, 1, bB);
        BAR;
        mmac(0, 1, bB);
        BAR;
        LOADA(1, 1);
        BAR;
        mmac(1, 1, bB);
        mmac(1, 0, bA);
    }
    #undef G256_TILE
    #undef LOADA
    #undef LOADB
    #undef BAR
    #undef VMW

    #pragma unroll
    for (int mi = 0; mi < 8; ++mi) {
        int row0 = bm + wm + mi * 16 + lq * 4;
        #pragma unroll
        for (int ni = 0; ni < 4; ++ni) {
            int col = bn + wn + ni * 16 + lr;
            float bv = bias[col];
            #pragma unroll
            for (int r = 0; r < 4; ++r) {
                float v = acc[mi][ni][r] + bv;
                size_t off = (size_t)(row0 + r) * N + col;
                if (MODE == 2) v = gelu_f(v);
                ((u16*)Cout)[off] = f2bf(v);
            }
        }
    }
}

// ---------------- Flash attention, band 512 + global-K tiles -----------------
// r10: Q fragments hoisted out of the K-loop (loop-invariant per wave; was
// re-read from LDS every tile) + T5 setprio around both MFMA clusters
// (3 independent blocks/CU at different phases -> scheduler can arbitrate).
__global__ __launch_bounds__(256) void attn_kernel(const u16* __restrict__ qh,
                                                   const u16* __restrict__ kh,
                                                   const u16* __restrict__ vt,
                                                   const unsigned long long* __restrict__ kmask,
                                                   u16* __restrict__ ctx) {
    const int qt = blockIdx.x, bh = blockIdx.y;
    const int b = bh >> 4, h = bh & 15;
    const int t = threadIdx.x, wv = t >> 6, lane = t & 63;
    const int lr = lane & 15, lq = lane >> 4;
    const int q0 = qt * 64;

    __shared__ __align__(16) u16 Qs[64 * 64];
    __shared__ __align__(16) u16 Ks[2][64 * 64];
    __shared__ __align__(16) u16 Vs[2][64 * 64];
    __shared__ __align__(16) u16 Ps[64 * 64];

    const u16* qbase = qh + ((size_t)bh * SS) * DH;
    const u16* kbase = kh + ((size_t)bh * SS) * DH;
    const u16* vbase = vt + ((size_t)bh * DH) * SS;

    #pragma unroll
    for (int p = 0; p < 2; ++p) {
        int c = p * 256 + t; int r = c >> 3, sl = c & 7;
        gld_lds16(qbase + (size_t)(q0 + r) * DH + ((sl ^ (r & 7)) * 8),
                  Qs + (size_t)(p * 256 + wv * 64) * 8);
    }

    float sum_part[4] = {0.f, 0.f, 0.f, 0.f};
    f32x4 acc_o[4] = {};

    const int lim = qt - 8;        // kt >= lim always included (band)
    int cur = 0;
    while (cur < lim && kmask[cur] == 0ull) ++cur;
    {
        int k0 = cur * 64;
        #pragma unroll
        for (int p = 0; p < 2; ++p) {
            int c = p * 256 + t; int r = c >> 3; int gc = ((c & 7) ^ (r & 7)) * 8;
            gld_lds16(kbase + (size_t)(k0 + r) * DH + gc, Ks[0] + (size_t)(p * 256 + wv * 64) * 8);
            gld_lds16(vbase + (size_t)r * SS + k0 + gc,  Vs[0] + (size_t)(p * 256 + wv * 64) * 8);
        }
    }
    // Q + tile0 staged; hoist the loop-invariant Q fragments into registers.
    __syncthreads();
    bf16x8 qf[2];
    {
        const int arow = wv * 16 + lr;
        qf[0] = *(const bf16x8*)&Qs[arow * 64 + (((0 * 4 + lq) ^ (arow & 7)) * 8)];
        qf[1] = *(const bf16x8*)&Qs[arow * 64 + (((1 * 4 + lq) ^ (arow & 7)) * 8)];
    }
    int pb = 0;
    while (cur >= 0) {
        int nxt = cur + 1;
        while (nxt < lim && kmask[nxt] == 0ull) ++nxt;
        if (nxt > qt) nxt = -1;
        __syncthreads();                       // buf pb ready for all waves
        if (nxt >= 0) {
            int k0n = nxt * 64;
            #pragma unroll
            for (int p = 0; p < 2; ++p) {
                int c = p * 256 + t; int r = c >> 3; int gc = ((c & 7) ^ (r & 7)) * 8;
                gld_lds16(kbase + (size_t)(k0n + r) * DH + gc, Ks[pb ^ 1] + (size_t)(p * 256 + wv * 64) * 8);
                gld_lds16(vbase + (size_t)r * SS + k0n + gc,  Vs[pb ^ 1] + (size_t)(p * 256 + wv * 64) * 8);
            }
        }
        const u16* Kt = Ks[pb];
        const u16* Vt = Vs[pb];
        const int k0 = cur * 64;

        f32x4 s_acc[4] = {};
        __builtin_amdgcn_s_setprio(1);
        #pragma unroll
        for (int ks = 0; ks < 2; ++ks) {
            #pragma unroll
            for (int ni = 0; ni < 4; ++ni) {
                const int brow = ni * 16 + lr;
                bf16x8 bfr = *(const bf16x8*)&Kt[brow * 64 + (((ks * 4 + lq) ^ (brow & 7)) * 8)];
                s_acc[ni] = __builtin_amdgcn_mfma_f32_16x16x32_bf16(qf[ks], bfr, s_acc[ni], 0, 0, 0);
            }
        }
        __builtin_amdgcn_s_setprio(0);
        float sv[4][4];
        if (cur >= qt - 7 && cur != qt) {                    // FULL
            #pragma unroll
            for (int ni = 0; ni < 4; ++ni)
                #pragma unroll
                for (int r = 0; r < 4; ++r) sv[ni][r] = __expf(s_acc[ni][r]);
        } else if (cur == qt) {                              // DIAG
            #pragma unroll
            for (int ni = 0; ni < 4; ++ni) {
                int j = ni * 16 + lr;
                #pragma unroll
                for (int r = 0; r < 4; ++r) {
                    int i = wv * 16 + lq * 4 + r;
                    float p = __expf(s_acc[ni][r]);
                    sv[ni][r] = (j <= i) ? p : 0.f;
                }
            }
        } else {                                             // MASKED
            unsigned long long cm = kmask[cur];
            #pragma unroll
            for (int ni = 0; ni < 4; ++ni) {
                int j = k0 + ni * 16 + lr;
                bool gj = (cm >> (ni * 16 + lr)) & 1ull;
                #pragma unroll
                for (int r = 0; r < 4; ++r) {
                    int i = q0 + wv * 16 + lq * 4 + r;
                    bool ok = ((i - j) < 512) | gj;
                    float p = __expf(s_acc[ni][r]);
                    sv[ni][r] = ok ? p : 0.f;
                }
            }
        }
        #pragma unroll
        for (int ni = 0; ni < 4; ++ni) {
            int col = ni * 16 + lr;
            #pragma unroll
            for (int r = 0; r < 4; ++r) {
                int row = wv * 16 + lq * 4 + r;
                sum_part[r] += sv[ni][r];
                Ps[row * 64 + (((col >> 3) ^ (row & 7)) * 8) + (col & 7)] = f2bf(sv[ni][r]);
            }
        }
        __builtin_amdgcn_s_setprio(1);
        #pragma unroll
        for (int ks = 0; ks < 2; ++ks) {
            const int arow = wv * 16 + lr;
            bf16x8 af = *(const bf16x8*)&Ps[arow * 64 + (((ks * 4 + lq) ^ (arow & 7)) * 8)];
            #pragma unroll
            for (int ni = 0; ni < 4; ++ni) {
                const int brow = ni * 16 + lr;
                bf16x8 bfr = *(const bf16x8*)&Vt[brow * 64 + (((ks * 4 + lq) ^ (brow & 7)) * 8)];
                acc_o[ni] = __builtin_amdgcn_mfma_f32_16x16x32_bf16(af, bfr, acc_o[ni], 0, 0, 0);
            }
        }
        __builtin_amdgcn_s_setprio(0);
        cur = nxt; pb ^= 1;
    }
    float inv_l[4];
    #pragma unroll
    for (int r = 0; r < 4; ++r) {
        float ls = sum_part[r];
        #pragma unroll
        for (int m = 1; m < 16; m <<= 1) ls += __shfl_xor(ls, m, 16);
        inv_l[r] = 1.f / ls;
    }
    u16* obase = ctx + ((size_t)b * SS) * DM + h * DH;
    #pragma unroll
    for (int ni = 0; ni < 4; ++ni)
        #pragma unroll
        for (int r = 0; r < 4; ++r) {
            int i = q0 + wv * 16 + lq * 4 + r;
            obase[(size_t)i * DM + ni * 16 + lr] = f2bf(acc_o[ni][r] * inv_l[r]);
        }
}

// ---------------- Global-row fixup: lane = key, zero in-loop cross-lane ops --
__global__ __launch_bounds__(256) void attn_fix_kernel(const u16* __restrict__ qh,
                                                       const u16* __restrict__ kh,
                                                       const u16* __restrict__ qkv,
                                                       const int* __restrict__ gti,
                                                       u16* __restrict__ ctx) {
    const int gidx = blockIdx.x, bh = blockIdx.y;
    const int b = bh >> 4, h = bh & 15;
    const int t = threadIdx.x, wv = t >> 6, lane = t & 63;
    const int i = gti[gidx];

    __shared__ float qsh[64];
    if (t < 64) qsh[t] = bf2f(qh[((size_t)bh * SS + i) * DH + t]);   // RoPE'd, prescaled
    __syncthreads();
    float qreg[64];
    #pragma unroll
    for (int c = 0; c < 16; ++c) {
        float4 qv = ((const float4*)qsh)[c];   // broadcast
        qreg[c * 4 + 0] = qv.x; qreg[c * 4 + 1] = qv.y;
        qreg[c * 4 + 2] = qv.z; qreg[c * 4 + 3] = qv.w;
    }

    const u16* kb = kh + (size_t)bh * SS * DH;
    const u16* vb = qkv + (size_t)b * SS * 3072 + 2048 + h * DH;

    float Oacc[64];
    #pragma unroll
    for (int d = 0; d < 64; ++d) Oacc[d] = 0.f;
    float lacc = 0.f;

    for (int j0 = wv * 64; j0 <= i; j0 += 256) {
        const int j = j0 + lane;
        const bool valid = (j <= i);
        const int jc = valid ? j : i;
        const s16x8* krow = (const s16x8*)(kb + (size_t)jc * DH);
        float part[8];
        #pragma unroll
        for (int c = 0; c < 8; ++c) {
            s16x8 kv = krow[c];
            float p0 = 0.f;
            #pragma unroll
            for (int e = 0; e < 8; ++e) p0 += qreg[c * 8 + e] * bf2f((u16)kv[e]);
            part[c] = p0;
        }
        float s = ((part[0] + part[1]) + (part[2] + part[3])) +
                  ((part[4] + part[5]) + (part[6] + part[7]));
        const float p = valid ? __expf(s) : 0.f;
        lacc += p;
        const s16x8* vrow = (const s16x8*)(vb + (size_t)jc * 3072);
        #pragma unroll
        for (int c = 0; c < 8; ++c) {
            s16x8 vv = vrow[c];
            #pragma unroll
            for (int e = 0; e < 8; ++e) Oacc[c * 8 + e] += p * bf2f((u16)vv[e]);
        }
    }
    #pragma unroll
    for (int m = 1; m < 64; m <<= 1) {
        lacc += __shfl_xor(lacc, m);
        #pragma unroll
        for (int d = 0; d < 64; ++d) Oacc[d] += __shfl_xor(Oacc[d], m);
    }
    float out = 0.f;
    #pragma unroll
    for (int d = 0; d < 64; ++d) out = (lane == d) ? Oacc[d] : out;
    __shared__ float osum[4][64];
    __shared__ float lsum[4];
    osum[wv][lane] = out;
    if (lane == 0) lsum[wv] = lacc;
    __syncthreads();
    if (wv == 0) {
        float ot = osum[0][lane] + osum[1][lane] + osum[2][lane] + osum[3][lane];
        float lt = lsum[0] + lsum[1] + lsum[2] + lsum[3];
        ctx[((size_t)b * SS + i) * DM + h * DH + lane] = f2bf(ot / lt);
    }
}

extern "C" void kernel_launch(void* const* d_in, const int* in_sizes, int n_in,
                              void* d_out, int out_size, void* d_ws, size_t ws_size,
                              hipStream_t stream) {
    (void)in_sizes; (void)n_in; (void)out_size; (void)ws_size;
    const float* hidden = (const float*)d_in[0];
    const float* ln1_g  = (const float*)d_in[1];
    const float* ln1_b  = (const float*)d_in[2];
    const float* wq = (const float*)d_in[3];  const float* bq = (const float*)d_in[4];
    const float* wk = (const float*)d_in[5];  const float* bk = (const float*)d_in[6];
    const float* wv = (const float*)d_in[7];  const float* bv = (const float*)d_in[8];
    const float* wo = (const float*)d_in[9];  const float* bo = (const float*)d_in[10];
    const float* ln2_g = (const float*)d_in[11];
    const float* ln2_b = (const float*)d_in[12];
    const float* w1 = (const float*)d_in[13]; const float* b1 = (const float*)d_in[14];
    const float* w2 = (const float*)d_in[15]; const float* b2 = (const float*)d_in[16];
    const int*  gti = (const int*)d_in[17];

    char* ws = (char*)d_ws;
    const size_t MB = 1u << 20;
    u16* wqt  = (u16*)(ws + 0 * MB);    // [3072][1024] contiguous (wq|wk|wv transposed)
    u16* wkt  = (u16*)(ws + 2 * MB);
    u16* wvt  = (u16*)(ws + 4 * MB);
    u16* wot  = (u16*)(ws + 6 * MB);
    u16* w1t  = (u16*)(ws + 8 * MB);    // [4096][1024]
    u16* w2t  = (u16*)(ws + 16 * MB);   // [1024][4096]
    u16* xb   = (u16*)(ws + 24 * MB);   // ln1 out; reused as ctx after QKV
    u16* ctx  = xb;
    u16* qkv  = (u16*)(ws + 32 * MB);   // [4096][3072] bf16, 24MB (32..56)
    u16* qhb  = (u16*)(ws + 56 * MB);
    u16* khb  = (u16*)(ws + 64 * MB);
    u16* vtb  = (u16*)(ws + 72 * MB);
    float* hb = (float*)(ws + 80 * MB); // fp32 residual h, 16MB
    u16* act  = (u16*)(ws + 32 * MB);   // 32MB (32..64): qkv+qhb dead after fixup
    u16* yb   = (u16*)(ws + 64 * MB);   // reuses khb (dead after fixup)
    unsigned long long* kmask = (unsigned long long*)(ws + 96 * MB);
    float* bias3 = (float*)(ws + 96 * MB + 8192);

    wtrans4_kernel<<<dim3(16, 16, 4), 256, 0, stream>>>(wq, wk, wv, wo, wqt, wkt, wvt, wot);
    wtrans_kernel<<<dim3(64, 16), 256, 0, stream>>>(w1, w1t, DM, DFF);
    wtrans_kernel<<<dim3(16, 64), 256, 0, stream>>>(w2, w2t, DFF, DM);
    build_aux<<<1, 256, 0, stream>>>(gti, kmask, bq, bk, bv, bias3);

    ln_kernel<false><<<NB * SS, 256, 0, stream>>>(hidden, ln1_g, ln1_b, xb, nullptr, nullptr);

    // fused QKV: A[4096x1024] * [wq|wk|wv]^T -> qkv[4096x3072]  (8-phase, free-sched)
    gemm256<0, 1><<<dim3(3072 / 256, (NB * SS) / 256), 512, 0, stream>>>(
        xb, wqt, bias3, qkv, NB * SS, 3072, DM, DM);

    rope_kernel<<<(NB * NH * SS * 32) / 256, 256, 0, stream>>>(qkv, qhb, khb);
    vtrans_kernel<<<dim3(SS / 64, NB * NH), 256, 0, stream>>>(qkv, vtb);

    attn_kernel<<<dim3(SS / 64, NB * NH), 256, 0, stream>>>(qhb, khb, vtb, kmask, ctx);
    attn_fix_kernel<<<dim3(8, NB * NH), 256, 0, stream>>>(qhb, khb, qkv, gti, ctx);

    gemm_bt<1, 1><<<dim3(8, 32), 256, 0, stream>>>(ctx, wot, bo, hidden, hb, NB * SS, DM, DM, DM);
    // ln2 + init d_out = h + b2 (accumulation target for split-K w2)
    ln_kernel<true><<<NB * SS, 256, 0, stream>>>(hb, ln2_g, ln2_b, yb, b2, (float*)d_out);
    // MLP GEMM1: gelu(y @ w1 + b1) -> act  (8-phase free-sched, 256 blocks = 1/CU)
    gemm256<2, 1><<<dim3(DFF / 256, (NB * SS) / 256), 512, 0, stream>>>(
        yb, w1t, b1, act, NB * SS, DFF, DM, DM);
    // MLP GEMM2: split-K=2 (512 blocks): d_out += act * w2t^T  (XCD-remapped)
    gemm_bt<3, 1><<<dim3(8, 32, 2), 256, 0, stream>>>(act, w2t, nullptr, nullptr, d_out, NB * SS, DM, DFF / 2, DFF);
}

// Round 11
// 380.265 us; speedup vs baseline: 1.3345x; 1.0111x over previous
//
#include <hip/hip_runtime.h>

typedef unsigned short u16;
typedef __bf16 bf16x8 __attribute__((ext_vector_type(8)));
typedef short s16x8 __attribute__((ext_vector_type(8)));
typedef float f32x4 __attribute__((ext_vector_type(4)));

#define NB 2
#define SS 2048
#define DM 1024
#define NH 16
#define DH 64
#define DFF 4096

__device__ __forceinline__ u16 f2bf(float f) {
    unsigned u = __float_as_uint(f);
    u += 0x7fff + ((u >> 16) & 1);   // RNE
    return (u16)(u >> 16);
}
__device__ __forceinline__ float bf2f(u16 h) {
    return __uint_as_float(((unsigned)h) << 16);
}
// async global->LDS, 16B per lane. LDS dest must be wave-uniform base + lane*16.
__device__ __forceinline__ void gld_lds16(const void* g, void* l) {
    __builtin_amdgcn_global_load_lds(
        (const __attribute__((address_space(1))) unsigned int*)(size_t)g,
        (__attribute__((address_space(3))) unsigned int*)(unsigned)(size_t)l,
        16, 0, 0);
}
__device__ __forceinline__ float gelu_f(float x) {
    return 0.5f * x * (1.f + erff(x * 0.70710678118654752f));
}

// ---------------- weight convert + transpose: w[K][N] fp32 -> wt[N][K] bf16 ----
__global__ void wtrans_kernel(const float* __restrict__ w, u16* __restrict__ wt,
                              int K, int N) {
    __shared__ unsigned tl[64][65];
    int n0 = blockIdx.x * 64, k0 = blockIdx.y * 64, t = threadIdx.x;
    for (int it = 0; it < 16; ++it) {
        int e = it * 256 + t; int r = e >> 6, c = e & 63;       // r: k, c: n
        tl[r][c] = f2bf(w[(size_t)(k0 + r) * N + n0 + c]);
    }
    __syncthreads();
    for (int it = 0; it < 16; ++it) {
        int e = it * 256 + t; int r = e >> 6, c = e & 63;       // r: n, c: k
        wt[(size_t)(n0 + r) * K + k0 + c] = (u16)tl[c][r];
    }
}

// batched version for the four 1024x1024 projection weights
__global__ void wtrans4_kernel(const float* __restrict__ a, const float* __restrict__ b,
                               const float* __restrict__ c, const float* __restrict__ d,
                               u16* __restrict__ oa, u16* __restrict__ ob,
                               u16* __restrict__ oc, u16* __restrict__ od) {
    __shared__ unsigned tl[64][65];
    const float* w; u16* wt;
    switch (blockIdx.z) {
        case 0: w = a; wt = oa; break;
        case 1: w = b; wt = ob; break;
        case 2: w = c; wt = oc; break;
        default: w = d; wt = od; break;
    }
    int n0 = blockIdx.x * 64, k0 = blockIdx.y * 64, t = threadIdx.x;
    for (int it = 0; it < 16; ++it) {
        int e = it * 256 + t; int r = e >> 6, cc = e & 63;
        tl[r][cc] = f2bf(w[(size_t)(k0 + r) * DM + n0 + cc]);
    }
    __syncthreads();
    for (int it = 0; it < 16; ++it) {
        int e = it * 256 + t; int r = e >> 6, cc = e & 63;
        wt[(size_t)(n0 + r) * DM + k0 + cc] = (u16)tl[cc][r];
    }
}

// ---------------- aux: per-k-tile global bitmasks + concat QKV bias ----------
__global__ void build_aux(const int* __restrict__ gti, unsigned long long* __restrict__ kmask,
                          const float* __restrict__ bq, const float* __restrict__ bk,
                          const float* __restrict__ bv, float* __restrict__ bias3) {
    int t = threadIdx.x;
    if (t < 32) {
        unsigned long long m = 0ull;
        #pragma unroll
        for (int i = 0; i < 8; ++i) {
            int g = gti[i];
            if ((g >> 6) == t) m |= 1ull << (g & 63);
        }
        kmask[t] = m;
    }
    for (int i = t; i < 1024; i += 256) {
        bias3[i] = bq[i]; bias3[1024 + i] = bk[i]; bias3[2048 + i] = bv[i];
    }
}

// ---------------- LayerNorm: fp32 in -> bf16 out; INIT also writes iout=x+ib --
template <bool INIT>
__global__ __launch_bounds__(256) void ln_kernel(const float* __restrict__ x,
                                                 const float* __restrict__ g,
                                                 const float* __restrict__ b,
                                                 u16* __restrict__ out,
                                                 const float* __restrict__ ib,
                                                 float* __restrict__ iout) {
    int row = blockIdx.x, t = threadIdx.x;
    const float4 v = ((const float4*)(x + (size_t)row * DM))[t];
    float s  = v.x + v.y + v.z + v.w;
    float sq = v.x * v.x + v.y * v.y + v.z * v.z + v.w * v.w;
    #pragma unroll
    for (int m = 1; m < 64; m <<= 1) { s += __shfl_xor(s, m); sq += __shfl_xor(sq, m); }
    __shared__ float ss[4], ssq[4];
    int wv = t >> 6, lane = t & 63;
    if (lane == 0) { ss[wv] = s; ssq[wv] = sq; }
    __syncthreads();
    s  = ss[0] + ss[1] + ss[2] + ss[3];
    sq = ssq[0] + ssq[1] + ssq[2] + ssq[3];
    float mean = s * (1.f / DM);
    float var  = sq * (1.f / DM) - mean * mean;
    float rs   = rsqrtf(var + 1e-5f);
    float4 gg = ((const float4*)g)[t];
    float4 bb = ((const float4*)b)[t];
    ushort4 o;
    o.x = f2bf((v.x - mean) * rs * gg.x + bb.x);
    o.y = f2bf((v.y - mean) * rs * gg.y + bb.y);
    o.z = f2bf((v.z - mean) * rs * gg.z + bb.z);
    o.w = f2bf((v.w - mean) * rs * gg.w + bb.w);
    ((ushort4*)(out + (size_t)row * DM))[t] = o;
    if (INIT) {
        float4 b2 = ((const float4*)ib)[t];
        float4 iv; iv.x = v.x + b2.x; iv.y = v.y + b2.y; iv.z = v.z + b2.z; iv.w = v.w + b2.w;
        ((float4*)(iout + (size_t)row * DM))[t] = iv;
    }
}

// ---------------- RoPE: qkv bf16 [B,S,3072] -> head-major bf16 [B,H,S,Dh] ----
// Q is prescaled by 1/sqrt(Dh)=0.125 so attention needs no score scaling.
__global__ __launch_bounds__(256) void rope_kernel(const u16* __restrict__ qkv,
                                                   u16* __restrict__ qh,
                                                   u16* __restrict__ kh) {
    int idx = blockIdx.x * 256 + threadIdx.x;   // B*H*S*32 threads
    int d = idx & 31;
    int s = (idx >> 5) & (SS - 1);
    int h = (idx >> 16) & (NH - 1);
    int b = idx >> 20;
    size_t src = ((size_t)(b * SS + s)) * 3072 + h * DH + d;
    size_t dst = ((size_t)((b * NH + h) * SS + s)) * DH + d;
    float inv = powf(10000.f, -(float)d * (1.f / 32.f));
    float ang = (float)s * inv;
    float sn, cs;
    sincosf(ang, &sn, &cs);
    const float QSC = 0.125f;
    float x1 = bf2f(qkv[src]), x2 = bf2f(qkv[src + 32]);
    qh[dst]      = f2bf((x1 * cs - x2 * sn) * QSC);
    qh[dst + 32] = f2bf((x2 * cs + x1 * sn) * QSC);
    x1 = bf2f(qkv[src + 1024]); x2 = bf2f(qkv[src + 1024 + 32]);
    kh[dst]      = f2bf(x1 * cs - x2 * sn);
    kh[dst + 32] = f2bf(x2 * cs + x1 * sn);
}

// ---------------- V transpose: qkv [B,S,3072] (v at +2048) -> [B,H,Dh,S] -----
__global__ __launch_bounds__(256) void vtrans_kernel(const u16* __restrict__ qkv,
                                                     u16* __restrict__ vt) {
    __shared__ unsigned tile[64][65];
    int st = blockIdx.x, bh = blockIdx.y;
    int b = bh >> 4, h = bh & 15, t = threadIdx.x;
    const u16* src = qkv + ((size_t)b * SS + st * 64) * 3072 + 2048 + h * DH;
    for (int it = 0; it < 16; ++it) {
        int e = it * 256 + t; int r = e >> 6, c = e & 63;       // r: s, c: d
        tile[r][c] = src[(size_t)r * 3072 + c];
    }
    __syncthreads();
    u16* dst = vt + ((size_t)bh * DH) * SS + st * 64;
    for (int it = 0; it < 16; ++it) {
        int e = it * 256 + t; int d = e >> 6, s = e & 63;
        dst[(size_t)d * SS + s] = (u16)tile[s][d];
    }
}

// XCD-aware remap: dispatch slot s -> (bn, bm, bz) so that slots on the same
// XCD (s & 7 under round-robin) share A-row panels (same bm chunk).
// Requires gridDim.y % 8 == 0.
__device__ __forceinline__ void xcd_remap(int& bn, int& bm, int& bz) {
    int s = blockIdx.x + gridDim.x * (blockIdx.y + gridDim.y * blockIdx.z);
    int q = gridDim.y >> 3;                  // bm chunk per XCD
    int xcd = s & 7, lin = s >> 3;
    bm = xcd * q + (lin % q);
    int rest = lin / q;
    bn = rest % gridDim.x;
    bz = rest / gridDim.x;
}

// ---------------- GEMM (legacy 128x128): C[M,N] = A[M,K](bf16) * Bt[N,K]^T ---
// MODE 1: +bias+res -> fp32 (Wo). MODE 3: split-K partial, atomicAdd fp32.
template <int MODE, int REMAP>
__global__ __launch_bounds__(256) void gemm_bt(const u16* __restrict__ A,
                                               const u16* __restrict__ Bt,
                                               const float* __restrict__ bias,
                                               const float* __restrict__ res,
                                               void* __restrict__ Cout,
                                               int M, int N, int K, int ldk) {
    int bnb = blockIdx.x, bmb = blockIdx.y, bzb = blockIdx.z;
    if (REMAP) xcd_remap(bnb, bmb, bzb);
    const int bm = bmb * 128, bn = bnb * 128;
    const int koff = bzb * K;
    const int t = threadIdx.x, wv = t >> 6, lane = t & 63;
    const int lr = lane & 15, lq = lane >> 4;
    const int wm = (wv >> 1) * 64, wn = (wv & 1) * 64;
    __shared__ __align__(16) u16 As[2][128 * 64];   // [m][k] swizzled, 16 KB each
    __shared__ __align__(16) u16 Bs[2][128 * 64];   // [n][k] swizzled
    f32x4 acc[4][4] = {};

    auto stage = [&](int kb, int buf) {
        #pragma unroll
        for (int p = 0; p < 4; ++p) {
            int c = p * 256 + t;                 // chunk id 0..1023, 16B each
            int r = c >> 3;                      // row 0..127
            int gc = ((c & 7) ^ (r & 7)) * 8;    // swizzled source column
            gld_lds16(A + (size_t)(bm + r) * ldk + kb + gc,
                      As[buf] + (size_t)(p * 256 + wv * 64) * 8);
            gld_lds16(Bt + (size_t)(bn + r) * ldk + kb + gc,
                      Bs[buf] + (size_t)(p * 256 + wv * 64) * 8);
        }
    };

    stage(koff, 0);
    int pb = 0;
    for (int k0 = 0; k0 < K; k0 += 64) {
        __syncthreads();                       // buf pb complete for all waves
        if (k0 + 64 < K) stage(koff + k0 + 64, pb ^ 1);
        const u16* Ac = As[pb];
        const u16* Bc = Bs[pb];
        #pragma unroll
        for (int ks = 0; ks < 2; ++ks) {
            bf16x8 af[4], bfr[4];
            #pragma unroll
            for (int mi = 0; mi < 4; ++mi) {
                int row = wm + mi * 16 + lr;
                af[mi] = *(const bf16x8*)&Ac[row * 64 + (((ks * 4 + lq) ^ (row & 7)) * 8)];
            }
            #pragma unroll
            for (int ni = 0; ni < 4; ++ni) {
                int row = wn + ni * 16 + lr;
                bfr[ni] = *(const bf16x8*)&Bc[row * 64 + (((ks * 4 + lq) ^ (row & 7)) * 8)];
            }
            #pragma unroll
            for (int mi = 0; mi < 4; ++mi)
                #pragma unroll
                for (int ni = 0; ni < 4; ++ni)
                    acc[mi][ni] = __builtin_amdgcn_mfma_f32_16x16x32_bf16(af[mi], bfr[ni], acc[mi][ni], 0, 0, 0);
        }
        pb ^= 1;
    }
    #pragma unroll
    for (int mi = 0; mi < 4; ++mi) {
        int row0 = bm + wm + mi * 16 + lq * 4;
        #pragma unroll
        for (int ni = 0; ni < 4; ++ni) {
            int col = bn + wn + ni * 16 + lr;
            float bv = (MODE == 3) ? 0.f : bias[col];
            #pragma unroll
            for (int r = 0; r < 4; ++r) {
                float v = acc[mi][ni][r] + bv;
                size_t off = (size_t)(row0 + r) * N + col;
                if (MODE == 1) v += res[off];
                if (MODE == 2) v = gelu_f(v);
                if (MODE == 0 || MODE == 2) ((u16*)Cout)[off] = f2bf(v);
                else if (MODE == 1)         ((float*)Cout)[off] = v;
                else                        atomicAdd((float*)Cout + off, v);
            }
        }
    }
}

// ---------------- GEMM 256x256: 8-phase, deep counted-vmcnt, imm-offset LDS --
// Schedule as round-3/4 EXCEPT: no lgkmcnt(0) drain and no sched_barrier(0)
// per phase. All LDS reads are compiler-visible C++ loads, so the compiler
// emits fine-grained counted lgkmcnt waits before each dependent MFMA and is
// free to overlap LDS-return latency with MFMA issue (m141 lesson: pinning
// the order defeats the scheduler). Correctness: each phase's ds_reads are
// consumed by that phase's MFMAs (so they complete before the end-of-phase
// barrier), and cross-wave staging WAR/RAW is ordered by the barriers + the
// unchanged counted-vmcnt ledger:
//   ph0 stages A1(kt+1); ph1: B1(kt+1); ph2: A0(kt+2); ph3: B0(kt+2);
//   end-ph0: vmcnt(6) retires through B1(kt); end-ph3: vmcnt(8) retires
//   A0(kt+1), B0(kt+1). Never drained to 0 in the main loop.
// MODE 0: +bias -> bf16 ; MODE 2: gelu(+bias) -> bf16.  Requires NT even >= 4.
template <int MODE, int REMAP>
__global__ __launch_bounds__(512, 2) void gemm256(const u16* __restrict__ A,
                                                  const u16* __restrict__ Bt,
                                                  const float* __restrict__ bias,
                                                  void* __restrict__ Cout,
                                                  int M, int N, int K, int ldk) {
    int bnb = blockIdx.x, bmb = blockIdx.y, bzb = blockIdx.z;
    if (REMAP) xcd_remap(bnb, bmb, bzb);
    const int bm = bmb * 256, bn = bnb * 256;
    const int t = threadIdx.x, wv = t >> 6, lane = t & 63;
    const int lr = lane & 15, lq = lane >> 4;
    const int wm = (wv >> 2) * 128, wn = (wv & 3) * 64;
    const int awb = (wv >> 2) * 64;          // A group-local wave base
    const int bwb = (wv & 3) * 32;           // B group-local wave base
    __shared__ __align__(16) u16 As[2 * 2 * 128 * 64];   // [db][grp][128][64]
    __shared__ __align__(16) u16 Bs[2 * 2 * 128 * 64];
    f32x4 acc[8][4] = {};
    bf16x8 aA[4][2], bA[2][2], bB[2][2];

    // 4 per-lane LDS base indices (u16 units); everything else is an immediate.
    const int aix0 = (awb + lr) * 64 + ((lq ^ (lr & 7)) * 8);
    const int aix1 = aix0 ^ 32;              // ks=1: slot^4 -> elem^32
    const int bix0 = (bwb + lr) * 64 + ((lq ^ (lr & 7)) * 8);
    const int bix1 = bix0 ^ 32;

    // per-thread pre-swizzled staging source pointers (2 loads per half-tile)
    const u16 *pAsrc[2][2], *pBsrc[2][2];
    #pragma unroll
    for (int g = 0; g < 2; ++g)
        #pragma unroll
        for (int p = 0; p < 2; ++p) {
            int c = p * 512 + t;                         // chunk 0..1023
            int glr = c >> 3, sl = c & 7;                // group-local row, slot
            int sc = (sl ^ (glr & 7)) * 8;               // pre-swizzled col
            int grA = (glr & 63) + g * 64 + ((glr >> 6) << 7);
            int grB = (glr & 31) + g * 32 + ((glr >> 5) << 6);
            pAsrc[g][p] = A  + (size_t)(bm + grA) * ldk + sc;
            pBsrc[g][p] = Bt + (size_t)(bn + grB) * ldk + sc;
        }
    auto stA = [&](int g, int db, int ku) {
        #pragma unroll
        for (int p = 0; p < 2; ++p)
            gld_lds16(pAsrc[g][p] + ku, As + (size_t)(db * 2 + g) * 8192
                                           + (size_t)(p * 512 + wv * 64) * 8);
    };
    auto stB = [&](int g, int db, int ku) {
        #pragma unroll
        for (int p = 0; p < 2; ++p)
            gld_lds16(pBsrc[g][p] + ku, Bs + (size_t)(db * 2 + g) * 8192
                                           + (size_t)(p * 512 + wv * 64) * 8);
    };
    auto mmac = [&](int qm, int qn, bf16x8 (&bb)[2][2]) {      // 16 MFMA
        __builtin_amdgcn_s_setprio(1);
        #pragma unroll
        for (int mi2 = 0; mi2 < 4; ++mi2)
            #pragma unroll
            for (int ni2 = 0; ni2 < 2; ++ni2)
                #pragma unroll
                for (int ks = 0; ks < 2; ++ks)
                    acc[qm * 4 + mi2][qn * 2 + ni2] =
                        __builtin_amdgcn_mfma_f32_16x16x32_bf16(
                            aA[mi2][ks], bb[ni2][ks], acc[qm * 4 + mi2][qn * 2 + ni2], 0, 0, 0);
        __builtin_amdgcn_s_setprio(0);
    };
    #define BAR       __builtin_amdgcn_s_barrier()
    #define VMW(n)    asm volatile("s_waitcnt vmcnt(" #n ")" ::: "memory")
    // all-immediate LDS fragment loads (DB, G literals at every call site)
    #define LOADA(DB, G) do {                                                  \
        constexpr int O_ = ((DB) * 2 + (G)) * 8192;                            \
        aA[0][0] = *(const bf16x8*)&As[aix0 + O_];                             \
        aA[0][1] = *(const bf16x8*)&As[aix1 + O_];                             \
        aA[1][0] = *(const bf16x8*)&As[aix0 + O_ + 1024];                      \
        aA[1][1] = *(const bf16x8*)&As[aix1 + O_ + 1024];                      \
        aA[2][0] = *(const bf16x8*)&As[aix0 + O_ + 2048];                      \
        aA[2][1] = *(const bf16x8*)&As[aix1 + O_ + 2048];                      \
        aA[3][0] = *(const bf16x8*)&As[aix0 + O_ + 3072];                      \
        aA[3][1] = *(const bf16x8*)&As[aix1 + O_ + 3072];                      \
    } while (0)
    #define LOADB(DB, G, DST) do {                                             \
        constexpr int O_ = ((DB) * 2 + (G)) * 8192;                            \
        DST[0][0] = *(const bf16x8*)&Bs[bix0 + O_];                            \
        DST[0][1] = *(const bf16x8*)&Bs[bix1 + O_];                            \
        DST[1][0] = *(const bf16x8*)&Bs[bix0 + O_ + 1024];                     \
        DST[1][1] = *(const bf16x8*)&Bs[bix1 + O_ + 1024];                     \
    } while (0)
    // one K-tile, DB literal; stages ku1 = (KT+1)<<6, ku2 = (KT+2)<<6
    #define G256_TILE(DB, KT) do {                                             \
        const int ku1 = ((KT) + 1) << 6, ku2 = ((KT) + 2) << 6;                \
        LOADA(DB, 0); LOADB(DB, 0, bA);          /* ph0: quadrant (0,0) */     \
        stA(1, (DB) ^ 1, ku1);                                                 \
        BAR;                                                                   \
        mmac(0, 0, bA);                                                        \
        VMW(6); BAR;                                                           \
        LOADB(DB, 1, bB);                        /* ph1: quadrant (0,1) */     \
        stB(1, (DB) ^ 1, ku1);                                                 \
        BAR;                                                                   \
        mmac(0, 1, bB);                                                        \
        BAR;                                                                   \
        LOADA(DB, 1);                            /* ph2: quadrant (1,1) */     \
        stA(0, DB, ku2);                                                       \
        BAR;                                                                   \
        mmac(1, 1, bB);                                                        \
        BAR;                                                                   \
        stB(0, DB, ku2);                         /* ph3: quadrant (1,0) */     \
        BAR;                                                                   \
        mmac(1, 0, bA);                                                        \
        VMW(8); BAR;                                                           \
    } while (0)

    const int NT = K >> 6;                 // K-tiles of 64; NT even, >= 4
    // prologue: fill pipeline with 6 half-tile groups (FIFO):
    //   A0(0),B0(0),A1(0),B1(0),A0(1),B0(1); retire the first four.
    stA(0, 0, 0); stB(0, 0, 0); stA(1, 0, 0); stB(1, 0, 0);
    stA(0, 1, 64); stB(0, 1, 64);
    VMW(8);
    BAR;

    for (int kt = 0; kt + 4 <= NT; kt += 2) {
        G256_TILE(0, kt);
        G256_TILE(1, kt + 1);
    }
    {   // peeled tile NT-2 (db = 0 since NT even): only A1/B1(NT-1) to issue
        const int ku1 = (NT - 1) << 6;
        LOADA(0, 0); LOADB(0, 0, bA);
        stA(1, 1, ku1);
        BAR;
        mmac(0, 0, bA);
        VMW(6);
        BAR;
        LOADB(0, 1, bB);
        stB(1, 1, ku1);
        BAR;
        mmac(0, 1, bB);
        BAR;
        LOADA(0, 1);
        BAR;
        mmac(1, 1, bB);
        BAR;
        mmac(1, 0, bA);
        VMW(4);                           // retire A0(NT-1), B0(NT-1)
        BAR;
    }
    {   // peeled tile NT-1 (last, db = 1): no staging
        LOADA(1, 0); LOADB(1, 0, bA);
        BAR;
        mmac(0, 0, bA);
        VMW(0);                           // retire A1,B1(NT-1)
        BAR;
        LOADB(1, 1, bB);
        BAR;
        mmac(0, 1, bB);
        BAR;
        LOADA(1, 1);
        BAR;
        mmac(1, 1, bB);
        mmac(1, 0, bA);
    }
    #undef G256_TILE
    #undef LOADA
    #undef LOADB
    #undef BAR
    #undef VMW

    #pragma unroll
    for (int mi = 0; mi < 8; ++mi) {
        int row0 = bm + wm + mi * 16 + lq * 4;
        #pragma unroll
        for (int ni = 0; ni < 4; ++ni) {
            int col = bn + wn + ni * 16 + lr;
            float bv = bias[col];
            #pragma unroll
            for (int r = 0; r < 4; ++r) {
                float v = acc[mi][ni][r] + bv;
                size_t off = (size_t)(row0 + r) * N + col;
                if (MODE == 2) v = gelu_f(v);
                ((u16*)Cout)[off] = f2bf(v);
            }
        }
    }
}

// ---------------- Flash attention, band 512 + global-K tiles -----------------
// r11: 128 q-rows per block (each wave owns 32 rows = 2 fragment rows).
// Tile count per (b,h) drops ~321 -> ~173 (band window amortized over 2x rows)
// at ~8% more MFMA -> ~46% less staging/barrier/loop overhead.
// Mask classes for k-tile kt (64 keys) vs q-block qt (128 rows):
//   kt >= 2qt           : DIAG   (causal j<=i; j>=q0 so band trivially holds)
//   2qt-6 <= kt < 2qt   : FULL   (worst pair i-j = 511 < 512; j < i)
//   kt <= 2qt-7         : MASKED ((i-j)<512 | global; j_max < i_min => causal ok)
// Skip: lim = max(0, 2qt-8); tiles >= lim always processed; end at kt > 2qt+1.
__global__ __launch_bounds__(256) void attn_kernel(const u16* __restrict__ qh,
                                                   const u16* __restrict__ kh,
                                                   const u16* __restrict__ vt,
                                                   const unsigned long long* __restrict__ kmask,
                                                   u16* __restrict__ ctx) {
    const int qt = blockIdx.x, bh = blockIdx.y;
    const int b = bh >> 4, h = bh & 15;
    const int t = threadIdx.x, wv = t >> 6, lane = t & 63;
    const int lr = lane & 15, lq = lane >> 4;
    const int q0 = qt * 128;

    __shared__ __align__(16) u16 Qs[128 * 64];
    __shared__ __align__(16) u16 Ks[2][64 * 64];
    __shared__ __align__(16) u16 Vs[2][64 * 64];
    __shared__ __align__(16) u16 Ps[128 * 64];

    const u16* qbase = qh + ((size_t)bh * SS) * DH;
    const u16* kbase = kh + ((size_t)bh * SS) * DH;
    const u16* vbase = vt + ((size_t)bh * DH) * SS;

    #pragma unroll
    for (int p = 0; p < 4; ++p) {
        int c = p * 256 + t; int r = c >> 3, sl = c & 7;
        gld_lds16(qbase + (size_t)(q0 + r) * DH + ((sl ^ (r & 7)) * 8),
                  Qs + (size_t)(p * 256 + wv * 64) * 8);
    }

    float sum_part[2][4] = {};
    f32x4 acc_o[2][4] = {};

    const int kend = 2 * qt + 1;
    const int lim = (2 * qt - 8 > 0) ? (2 * qt - 8) : 0;
    int cur = 0;
    while (cur < lim && kmask[cur] == 0ull) ++cur;
    {
        int k0 = cur * 64;
        #pragma unroll
        for (int p = 0; p < 2; ++p) {
            int c = p * 256 + t; int r = c >> 3; int gc = ((c & 7) ^ (r & 7)) * 8;
            gld_lds16(kbase + (size_t)(k0 + r) * DH + gc, Ks[0] + (size_t)(p * 256 + wv * 64) * 8);
            gld_lds16(vbase + (size_t)r * SS + k0 + gc,  Vs[0] + (size_t)(p * 256 + wv * 64) * 8);
        }
    }
    // Q + tile0 staged; hoist the loop-invariant Q fragments into registers.
    __syncthreads();
    bf16x8 qf[2][2];
    #pragma unroll
    for (int f = 0; f < 2; ++f) {
        const int arow = wv * 32 + f * 16 + lr;
        qf[f][0] = *(const bf16x8*)&Qs[arow * 64 + (((0 * 4 + lq) ^ (arow & 7)) * 8)];
        qf[f][1] = *(const bf16x8*)&Qs[arow * 64 + (((1 * 4 + lq) ^ (arow & 7)) * 8)];
    }
    int pb = 0;
    while (cur >= 0) {
        int nxt = cur + 1;
        while (nxt < lim && kmask[nxt] == 0ull) ++nxt;
        if (nxt > kend) nxt = -1;
        __syncthreads();                       // buf pb ready for all waves
        if (nxt >= 0) {
            int k0n = nxt * 64;
            #pragma unroll
            for (int p = 0; p < 2; ++p) {
                int c = p * 256 + t; int r = c >> 3; int gc = ((c & 7) ^ (r & 7)) * 8;
                gld_lds16(kbase + (size_t)(k0n + r) * DH + gc, Ks[pb ^ 1] + (size_t)(p * 256 + wv * 64) * 8);
                gld_lds16(vbase + (size_t)r * SS + k0n + gc,  Vs[pb ^ 1] + (size_t)(p * 256 + wv * 64) * 8);
            }
        }
        const u16* Kt = Ks[pb];
        const u16* Vt = Vs[pb];
        const int k0 = cur * 64;

        f32x4 s_acc[2][4] = {};
        __builtin_amdgcn_s_setprio(1);
        #pragma unroll
        for (int ks = 0; ks < 2; ++ks) {
            #pragma unroll
            for (int ni = 0; ni < 4; ++ni) {
                const int brow = ni * 16 + lr;
                bf16x8 bfr = *(const bf16x8*)&Kt[brow * 64 + (((ks * 4 + lq) ^ (brow & 7)) * 8)];
                #pragma unroll
                for (int f = 0; f < 2; ++f)
                    s_acc[f][ni] = __builtin_amdgcn_mfma_f32_16x16x32_bf16(qf[f][ks], bfr, s_acc[f][ni], 0, 0, 0);
            }
        }
        __builtin_amdgcn_s_setprio(0);
        float sv[2][4][4];
        if (cur >= 2 * qt) {                                 // DIAG: causal only
            #pragma unroll
            for (int f = 0; f < 2; ++f)
                #pragma unroll
                for (int ni = 0; ni < 4; ++ni) {
                    int j = k0 + ni * 16 + lr;
                    #pragma unroll
                    for (int r = 0; r < 4; ++r) {
                        int i = q0 + wv * 32 + f * 16 + lq * 4 + r;
                        float p = __expf(s_acc[f][ni][r]);
                        sv[f][ni][r] = (j <= i) ? p : 0.f;
                    }
                }
        } else if (cur >= 2 * qt - 6) {                      // FULL
            #pragma unroll
            for (int f = 0; f < 2; ++f)
                #pragma unroll
                for (int ni = 0; ni < 4; ++ni)
                    #pragma unroll
                    for (int r = 0; r < 4; ++r) sv[f][ni][r] = __expf(s_acc[f][ni][r]);
        } else {                                             // MASKED
            unsigned long long cm = kmask[cur];
            #pragma unroll
            for (int f = 0; f < 2; ++f)
                #pragma unroll
                for (int ni = 0; ni < 4; ++ni) {
                    int j = k0 + ni * 16 + lr;
                    bool gj = (cm >> (ni * 16 + lr)) & 1ull;
                    #pragma unroll
                    for (int r = 0; r < 4; ++r) {
                        int i = q0 + wv * 32 + f * 16 + lq * 4 + r;
                        bool ok = ((i - j) < 512) | gj;
                        float p = __expf(s_acc[f][ni][r]);
                        sv[f][ni][r] = ok ? p : 0.f;
                    }
                }
        }
        #pragma unroll
        for (int f = 0; f < 2; ++f)
            #pragma unroll
            for (int ni = 0; ni < 4; ++ni) {
                int col = ni * 16 + lr;
                #pragma unroll
                for (int r = 0; r < 4; ++r) {
                    int row = wv * 32 + f * 16 + lq * 4 + r;
                    sum_part[f][r] += sv[f][ni][r];
                    Ps[row * 64 + (((col >> 3) ^ (row & 7)) * 8) + (col & 7)] = f2bf(sv[f][ni][r]);
                }
            }
        __builtin_amdgcn_s_setprio(1);
        #pragma unroll
        for (int ks = 0; ks < 2; ++ks) {
            #pragma unroll
            for (int f = 0; f < 2; ++f) {
                const int arow = wv * 32 + f * 16 + lr;
                bf16x8 af = *(const bf16x8*)&Ps[arow * 64 + (((ks * 4 + lq) ^ (arow & 7)) * 8)];
                #pragma unroll
                for (int ni = 0; ni < 4; ++ni) {
                    const int brow = ni * 16 + lr;
                    bf16x8 bfr = *(const bf16x8*)&Vt[brow * 64 + (((ks * 4 + lq) ^ (brow & 7)) * 8)];
                    acc_o[f][ni] = __builtin_amdgcn_mfma_f32_16x16x32_bf16(af, bfr, acc_o[f][ni], 0, 0, 0);
                }
            }
        }
        __builtin_amdgcn_s_setprio(0);
        cur = nxt; pb ^= 1;
    }
    float inv_l[2][4];
    #pragma unroll
    for (int f = 0; f < 2; ++f)
        #pragma unroll
        for (int r = 0; r < 4; ++r) {
            float ls = sum_part[f][r];
            #pragma unroll
            for (int m = 1; m < 16; m <<= 1) ls += __shfl_xor(ls, m, 16);
            inv_l[f][r] = 1.f / ls;
        }
    u16* obase = ctx + ((size_t)b * SS) * DM + h * DH;
    #pragma unroll
    for (int f = 0; f < 2; ++f)
        #pragma unroll
        for (int ni = 0; ni < 4; ++ni)
            #pragma unroll
            for (int r = 0; r < 4; ++r) {
                int i = q0 + wv * 32 + f * 16 + lq * 4 + r;
                obase[(size_t)i * DM + ni * 16 + lr] = f2bf(acc_o[f][ni][r] * inv_l[f][r]);
            }
}

// ---------------- Global-row fixup: lane = key, zero in-loop cross-lane ops --
__global__ __launch_bounds__(256) void attn_fix_kernel(const u16* __restrict__ qh,
                                                       const u16* __restrict__ kh,
                                                       const u16* __restrict__ qkv,
                                                       const int* __restrict__ gti,
                                                       u16* __restrict__ ctx) {
    const int gidx = blockIdx.x, bh = blockIdx.y;
    const int b = bh >> 4, h = bh & 15;
    const int t = threadIdx.x, wv = t >> 6, lane = t & 63;
    const int i = gti[gidx];

    __shared__ float qsh[64];
    if (t < 64) qsh[t] = bf2f(qh[((size_t)bh * SS + i) * DH + t]);   // RoPE'd, prescaled
    __syncthreads();
    float qreg[64];
    #pragma unroll
    for (int c = 0; c < 16; ++c) {
        float4 qv = ((const float4*)qsh)[c];   // broadcast
        qreg[c * 4 + 0] = qv.x; qreg[c * 4 + 1] = qv.y;
        qreg[c * 4 + 2] = qv.z; qreg[c * 4 + 3] = qv.w;
    }

    const u16* kb = kh + (size_t)bh * SS * DH;
    const u16* vb = qkv + (size_t)b * SS * 3072 + 2048 + h * DH;

    float Oacc[64];
    #pragma unroll
    for (int d = 0; d < 64; ++d) Oacc[d] = 0.f;
    float lacc = 0.f;

    for (int j0 = wv * 64; j0 <= i; j0 += 256) {
        const int j = j0 + lane;
        const bool valid = (j <= i);
        const int jc = valid ? j : i;
        const s16x8* krow = (const s16x8*)(kb + (size_t)jc * DH);
        float part[8];
        #pragma unroll
        for (int c = 0; c < 8; ++c) {
            s16x8 kv = krow[c];
            float p0 = 0.f;
            #pragma unroll
            for (int e = 0; e < 8; ++e) p0 += qreg[c * 8 + e] * bf2f((u16)kv[e]);
            part[c] = p0;
        }
        float s = ((part[0] + part[1]) + (part[2] + part[3])) +
                  ((part[4] + part[5]) + (part[6] + part[7]));
        const float p = valid ? __expf(s) : 0.f;
        lacc += p;
        const s16x8* vrow = (const s16x8*)(vb + (size_t)jc * 3072);
        #pragma unroll
        for (int c = 0; c < 8; ++c) {
            s16x8 vv = vrow[c];
            #pragma unroll
            for (int e = 0; e < 8; ++e) Oacc[c * 8 + e] += p * bf2f((u16)vv[e]);
        }
    }
    #pragma unroll
    for (int m = 1; m < 64; m <<= 1) {
        lacc += __shfl_xor(lacc, m);
        #pragma unroll
        for (int d = 0; d < 64; ++d) Oacc[d] += __shfl_xor(Oacc[d], m);
    }
    float out = 0.f;
    #pragma unroll
    for (int d = 0; d < 64; ++d) out = (lane == d) ? Oacc[d] : out;
    __shared__ float osum[4][64];
    __shared__ float lsum[4];
    osum[wv][lane] = out;
    if (lane == 0) lsum[wv] = lacc;
    __syncthreads();
    if (wv == 0) {
        float ot = osum[0][lane] + osum[1][lane] + osum[2][lane] + osum[3][lane];
        float lt = lsum[0] + lsum[1] + lsum[2] + lsum[3];
        ctx[((size_t)b * SS + i) * DM + h * DH + lane] = f2bf(ot / lt);
    }
}

extern "C" void kernel_launch(void* const* d_in, const int* in_sizes, int n_in,
                              void* d_out, int out_size, void* d_ws, size_t ws_size,
                              hipStream_t stream) {
    (void)in_sizes; (void)n_in; (void)out_size; (void)ws_size;
    const float* hidden = (const float*)d_in[0];
    const float* ln1_g  = (const float*)d_in[1];
    const float* ln1_b  = (const float*)d_in[2];
    const float* wq = (const float*)d_in[3];  const float* bq = (const float*)d_in[4];
    const float* wk = (const float*)d_in[5];  const float* bk = (const float*)d_in[6];
    const float* wv = (const float*)d_in[7];  const float* bv = (const float*)d_in[8];
    const float* wo = (const float*)d_in[9];  const float* bo = (const float*)d_in[10];
    const float* ln2_g = (const float*)d_in[11];
    const float* ln2_b = (const float*)d_in[12];
    const float* w1 = (const float*)d_in[13]; const float* b1 = (const float*)d_in[14];
    const float* w2 = (const float*)d_in[15]; const float* b2 = (const float*)d_in[16];
    const int*  gti = (const int*)d_in[17];

    char* ws = (char*)d_ws;
    const size_t MB = 1u << 20;
    u16* wqt  = (u16*)(ws + 0 * MB);    // [3072][1024] contiguous (wq|wk|wv transposed)
    u16* wkt  = (u16*)(ws + 2 * MB);
    u16* wvt  = (u16*)(ws + 4 * MB);
    u16* wot  = (u16*)(ws + 6 * MB);
    u16* w1t  = (u16*)(ws + 8 * MB);    // [4096][1024]
    u16* w2t  = (u16*)(ws + 16 * MB);   // [1024][4096]
    u16* xb   = (u16*)(ws + 24 * MB);   // ln1 out; reused as ctx after QKV
    u16* ctx  = xb;
    u16* qkv  = (u16*)(ws + 32 * MB);   // [4096][3072] bf16, 24MB (32..56)
    u16* qhb  = (u16*)(ws + 56 * MB);
    u16* khb  = (u16*)(ws + 64 * MB);
    u16* vtb  = (u16*)(ws + 72 * MB);
    float* hb = (float*)(ws + 80 * MB); // fp32 residual h, 16MB
    u16* act  = (u16*)(ws + 32 * MB);   // 32MB (32..64): qkv+qhb dead after fixup
    u16* yb   = (u16*)(ws + 64 * MB);   // reuses khb (dead after fixup)
    unsigned long long* kmask = (unsigned long long*)(ws + 96 * MB);
    float* bias3 = (float*)(ws + 96 * MB + 8192);

    wtrans4_kernel<<<dim3(16, 16, 4), 256, 0, stream>>>(wq, wk, wv, wo, wqt, wkt, wvt, wot);
    wtrans_kernel<<<dim3(64, 16), 256, 0, stream>>>(w1, w1t, DM, DFF);
    wtrans_kernel<<<dim3(16, 64), 256, 0, stream>>>(w2, w2t, DFF, DM);
    build_aux<<<1, 256, 0, stream>>>(gti, kmask, bq, bk, bv, bias3);

    ln_kernel<false><<<NB * SS, 256, 0, stream>>>(hidden, ln1_g, ln1_b, xb, nullptr, nullptr);

    // fused QKV: A[4096x1024] * [wq|wk|wv]^T -> qkv[4096x3072]  (8-phase, free-sched)
    gemm256<0, 1><<<dim3(3072 / 256, (NB * SS) / 256), 512, 0, stream>>>(
        xb, wqt, bias3, qkv, NB * SS, 3072, DM, DM);

    rope_kernel<<<(NB * NH * SS * 32) / 256, 256, 0, stream>>>(qkv, qhb, khb);
    vtrans_kernel<<<dim3(SS / 64, NB * NH), 256, 0, stream>>>(qkv, vtb);

    attn_kernel<<<dim3(SS / 128, NB * NH), 256, 0, stream>>>(qhb, khb, vtb, kmask, ctx);
    attn_fix_kernel<<<dim3(8, NB * NH), 256, 0, stream>>>(qhb, khb, qkv, gti, ctx);

    gemm_bt<1, 1><<<dim3(8, 32), 256, 0, stream>>>(ctx, wot, bo, hidden, hb, NB * SS, DM, DM, DM);
    // ln2 + init d_out = h + b2 (accumulation target for split-K w2)
    ln_kernel<true><<<NB * SS, 256, 0, stream>>>(hb, ln2_g, ln2_b, yb, b2, (float*)d_out);
    // MLP GEMM1: gelu(y @ w1 + b1) -> act  (8-phase free-sched, 256 blocks = 1/CU)
    gemm256<2, 1><<<dim3(DFF / 256, (NB * SS) / 256), 512, 0, stream>>>(
        yb, w1t, b1, act, NB * SS, DFF, DM, DM);
    // MLP GEMM2: split-K=2 (512 blocks): d_out += act * w2t^T  (XCD-remapped)
    gemm_bt<3, 1><<<dim3(8, 32, 2), 256, 0, stream>>>(act, w2t, nullptr, nullptr, d_out, NB * SS, DM, DFF / 2, DFF);
}